// Round 2
// baseline (3661.565 us; speedup 1.0000x reference)
//
#include <hip/hip_runtime.h>
#include <math.h>

#define NPOS  65536          // B*H*W
#define LL    16384          // H*W
#define SCALE_F 0.08838834764831843f

// ---------------------------------------------------------------------------
// K1: fused window/bra QKV GEMM.  per position: x[0:64]@wqkv_w, x[64:128]@bqkv_w
// grid 1024, block 384 (one output channel per thread, 64 positions per block)
// ---------------------------------------------------------------------------
__global__ void k_qkv(const float* __restrict__ x,
                      const float* __restrict__ ww, const float* __restrict__ wb,
                      const float* __restrict__ bw, const float* __restrict__ bbias,
                      float* __restrict__ wqkv, float* __restrict__ bqkv)
{
    __shared__ float xs[64 * 128];
    const int p0 = blockIdx.x * 64;
    const int tid = threadIdx.x;
    for (int i = tid; i < 64 * 128; i += 384) xs[i] = x[(size_t)p0 * 128 + i];

    const int c = tid;
    float wreg[64];
    float bias;
    int koff;
    if (c < 192) {
#pragma unroll
        for (int k = 0; k < 64; k++) wreg[k] = ww[k * 192 + c];
        bias = wb[c];
        koff = 0;
    } else {
        const int cc = c - 192;
#pragma unroll
        for (int k = 0; k < 64; k++) wreg[k] = bw[k * 192 + cc];
        bias = bbias[cc];
        koff = 64;
    }
    __syncthreads();
    for (int p = 0; p < 64; p++) {
        float acc = bias;
        const float* xr = &xs[p * 128 + koff];
#pragma unroll
        for (int k = 0; k < 64; k++) acc = fmaf(xr[k], wreg[k], acc);
        if (c < 192) wqkv[(size_t)(p0 + p) * 192 + c] = acc;
        else         bqkv[(size_t)(p0 + p) * 192 + (c - 192)] = acc;
    }
}

// ---------------------------------------------------------------------------
// K2: depthwise 3x3 LEPE conv on vcat = [bqkv.v (ch 0..63), wqkv.v (ch 64..127)]
// writes lepe into out3 (B, L, 128).  grid 65536, block 128
// ---------------------------------------------------------------------------
__global__ void k_conv(const float* __restrict__ wqkv, const float* __restrict__ bqkv,
                       const float* __restrict__ cw, const float* __restrict__ cb,
                       float* __restrict__ out3)
{
    const int pos = blockIdx.x;
    const int c = threadIdx.x;
    const int b = pos >> 14;
    const int hw = pos & 16383;
    const int h = hw >> 7;
    const int w = hw & 127;
    const float* src = (c < 64) ? (bqkv + 128 + c) : (wqkv + 128 + (c - 64));
    float acc = cb[c];
#pragma unroll
    for (int dh = -1; dh <= 1; dh++) {
        const int h2 = h + dh;
        if (h2 < 0 || h2 >= 128) continue;
#pragma unroll
        for (int dw = -1; dw <= 1; dw++) {
            const int w2 = w + dw;
            if (w2 < 0 || w2 >= 128) continue;
            const size_t row = ((size_t)b * 16384 + h2 * 128 + w2) * 192;
            acc = fmaf(src[row], cw[c * 9 + (dh + 1) * 3 + (dw + 1)], acc);
        }
    }
    out3[(size_t)pos * 128 + c] = acc;
}

// ---------------------------------------------------------------------------
// K3: window attention.  grid 8192 = (b,hr,wr,head), block 64 (query pos)
// adds into out3 channels [0,64)
// ---------------------------------------------------------------------------
__global__ void k_win(const float* __restrict__ wqkv, float* __restrict__ out3)
{
    const int bid = blockIdx.x;
    const int n = bid & 7;
    const int win = bid >> 3;
    const int wr = win & 15;
    const int hr = (win >> 4) & 15;
    const int b = win >> 8;
    const int p = threadIdx.x;
    const int wi = p >> 3, wj = p & 7;
    const int h = hr * 8 + wi, w = wr * 8 + wj;
    const size_t row = ((size_t)b * 16384 + h * 128 + w) * 192;

    __shared__ float kk[64][8];
    __shared__ float vv[64][8];
    float q[8];
#pragma unroll
    for (int d = 0; d < 8; d++) {
        q[d] = wqkv[row + n * 8 + d] * SCALE_F;
        kk[p][d] = wqkv[row + 64 + n * 8 + d];
        vv[p][d] = wqkv[row + 128 + n * 8 + d];
    }
    __syncthreads();

    float s[64];
    float m = -1e30f;
#pragma unroll
    for (int j = 0; j < 64; j++) {
        float a = 0.f;
#pragma unroll
        for (int d = 0; d < 8; d++) a = fmaf(q[d], kk[j][d], a);
        s[j] = a;
        m = fmaxf(m, a);
    }
    float sum = 0.f;
#pragma unroll
    for (int j = 0; j < 64; j++) {
        s[j] = expf(s[j] - m);
        sum += s[j];
    }
    const float inv = 1.0f / sum;
    float o[8] = {0.f, 0.f, 0.f, 0.f, 0.f, 0.f, 0.f, 0.f};
#pragma unroll
    for (int j = 0; j < 64; j++) {
        const float pj = s[j] * inv;
#pragma unroll
        for (int d = 0; d < 8; d++) o[d] = fmaf(pj, vv[j][d], o[d]);
    }
    const size_t orow = ((size_t)b * 16384 + h * 128 + w) * 128;
#pragma unroll
    for (int d = 0; d < 8; d++) out3[orow + n * 8 + d] += o[d];
}

// ---------------------------------------------------------------------------
// K4: 8x8 window mean-pool of bra q and k.  grid 1024 = (b, region), block 64 (ch)
// ---------------------------------------------------------------------------
__global__ void k_pool(const float* __restrict__ bqkv,
                       float* __restrict__ pq, float* __restrict__ pk)
{
    const int r = blockIdx.x;
    const int b = r >> 8;
    const int reg = r & 255;
    const int hr = reg >> 4, wr = reg & 15;
    const int c = threadIdx.x;
    float sq = 0.f, sk = 0.f;
    for (int wi = 0; wi < 8; wi++)
        for (int wj = 0; wj < 8; wj++) {
            const size_t row = ((size_t)b * 16384 + (hr * 8 + wi) * 128 + (wr * 8 + wj)) * 192;
            sq += bqkv[row + c];
            sk += bqkv[row + 64 + c];
        }
    pq[(size_t)r * 64 + c] = sq * (1.0f / 64.0f);
    pk[(size_t)r * 64 + c] = sk * (1.0f / 64.0f);
}

// ---------------------------------------------------------------------------
// K5: routing scores + stable top-4.  grid 1024 = (b, i), block 64
// ---------------------------------------------------------------------------
__global__ void k_topk(const float* __restrict__ pq, const float* __restrict__ pk,
                       int* __restrict__ idx)
{
    const int bi = blockIdx.x;
    const int b = bi >> 8;
    const int t = threadIdx.x;
    __shared__ float qrow[64];
    __shared__ float s[256];
    qrow[t] = pq[(size_t)bi * 64 + t];
    __syncthreads();
    for (int j4 = 0; j4 < 4; j4++) {
        const int j = j4 * 64 + t;
        const float* krow = pk + ((size_t)b * 256 + j) * 64;
        float a = 0.f;
#pragma unroll
        for (int c = 0; c < 64; c++) a = fmaf(qrow[c], krow[c], a);
        s[j] = a;
    }
    __syncthreads();
    if (t == 0) {
        int chosen[4];
        for (int sel = 0; sel < 4; sel++) {
            float best = -1e30f;
            int bj = -1;
            for (int j = 0; j < 256; j++) {
                bool skip = false;
                for (int u = 0; u < sel; u++) skip = skip || (chosen[u] == j);
                if (!skip && s[j] > best) { best = s[j]; bj = j; }
            }
            chosen[sel] = bj;
            idx[bi * 4 + sel] = bj;
        }
    }
}

// ---------------------------------------------------------------------------
// K6: gathered BRA attention.  grid 8192 = (b, head, region), block 64 (query pos)
// adds into out3 channels [64,128)
// ---------------------------------------------------------------------------
__global__ void k_bra(const float* __restrict__ bqkv, const int* __restrict__ idx,
                      float* __restrict__ out3)
{
    const int r = blockIdx.x & 255;
    const int n = (blockIdx.x >> 8) & 7;
    const int b = blockIdx.x >> 11;
    const int p = threadIdx.x;
    const int wi = p >> 3, wj = p & 7;

    __shared__ float kk[256][8];
    __shared__ float vv[256][8];
    __shared__ int regs[4];
    if (p < 4) regs[p] = idx[((b << 8) + r) * 4 + p];
    __syncthreads();

    for (int t = 0; t < 4; t++) {
        const int rt = regs[t];
        const int hr = rt >> 4, wr2 = rt & 15;
        const size_t row = ((size_t)b * 16384 + (hr * 8 + wi) * 128 + (wr2 * 8 + wj)) * 192;
#pragma unroll
        for (int d = 0; d < 8; d++) {
            kk[t * 64 + p][d] = bqkv[row + 64 + n * 8 + d];
            vv[t * 64 + p][d] = bqkv[row + 128 + n * 8 + d];
        }
    }
    const int hq = (r >> 4) * 8 + wi, wq = (r & 15) * 8 + wj;
    const size_t qoff = ((size_t)b * 16384 + hq * 128 + wq) * 192;
    float q[8];
#pragma unroll
    for (int d = 0; d < 8; d++) q[d] = bqkv[qoff + n * 8 + d] * SCALE_F;
    __syncthreads();

    float m = -1e30f;
    for (int j = 0; j < 256; j++) {
        float a = 0.f;
#pragma unroll
        for (int d = 0; d < 8; d++) a = fmaf(q[d], kk[j][d], a);
        m = fmaxf(m, a);
    }
    float sum = 0.f;
    float o[8] = {0.f, 0.f, 0.f, 0.f, 0.f, 0.f, 0.f, 0.f};
    for (int j = 0; j < 256; j++) {
        float a = 0.f;
#pragma unroll
        for (int d = 0; d < 8; d++) a = fmaf(q[d], kk[j][d], a);
        const float e = expf(a - m);
        sum += e;
#pragma unroll
        for (int d = 0; d < 8; d++) o[d] = fmaf(e, vv[j][d], o[d]);
    }
    const float inv = 1.0f / sum;
    const size_t orow = ((size_t)b * 16384 + hq * 128 + wq) * 128;
#pragma unroll
    for (int d = 0; d < 8; d++) out3[orow + 64 + n * 8 + d] += o[d] * inv;
}

// ---------------------------------------------------------------------------
// K7: channel-attn QKV GEMM, output transposed to (3, B, NH, 16, L)
// grid 1024, block 384
// ---------------------------------------------------------------------------
__global__ void k_cqkv(const float* __restrict__ out3, const float* __restrict__ qw,
                       const float* __restrict__ qb, float* __restrict__ cq)
{
    __shared__ float xs[64 * 128];
    const int p0 = blockIdx.x * 64;
    const int tid = threadIdx.x;
    for (int i = tid; i < 64 * 128; i += 384) xs[i] = out3[(size_t)p0 * 128 + i];

    const int c = tid;
    float wreg[128];
#pragma unroll
    for (int k = 0; k < 128; k++) wreg[k] = qw[k * 384 + c];
    const float bias = qb[c];
    const int s = c >> 7;
    const int cc = c & 127;
    const int n = cc >> 4;
    const int d = cc & 15;
    __syncthreads();
    for (int p = 0; p < 64; p++) {
        float acc = bias;
        const float* xr = &xs[p * 128];
#pragma unroll
        for (int k = 0; k < 128; k++) acc = fmaf(xr[k], wreg[k], acc);
        const int P = p0 + p;
        const int b = P >> 14;
        const int l = P & 16383;
        cq[((((size_t)s * 4 + b) * 8 + n) * 16 + d) * 16384 + l] = acc;
    }
}

// ---------------------------------------------------------------------------
// K8: L2 norms of cq, ck rows.  grid 1024 rows (q rows 0..511, k rows 512..1023)
// ---------------------------------------------------------------------------
__global__ void k_norm(const float* __restrict__ cq, float* __restrict__ invn)
{
    __shared__ float red[256];
    const int row = blockIdx.x;
    const int t = threadIdx.x;
    const float* xr = cq + (size_t)row * 16384;
    float acc = 0.f;
    for (int i = t; i < 16384; i += 256) {
        const float v = xr[i];
        acc = fmaf(v, v, acc);
    }
    red[t] = acc;
    __syncthreads();
    for (int off = 128; off > 0; off >>= 1) {
        if (t < off) red[t] += red[t + off];
        __syncthreads();
    }
    if (t == 0) invn[row] = 1.0f / fmaxf(sqrtf(red[0]), 1e-12f);
}

// ---------------------------------------------------------------------------
// K9: channel attention 16x16 Gram + softmax.  grid 32 = (b, n), block 256 = (d, e)
// ---------------------------------------------------------------------------
__global__ void k_cattn(const float* __restrict__ cq, const float* __restrict__ invn,
                        const float* __restrict__ temp, float* __restrict__ cattn)
{
    const int bn = blockIdx.x;
    const int t = threadIdx.x;
    const int d = t >> 4;
    const int e = t & 15;
    __shared__ float qs[16][132];
    __shared__ float ks[16][132];
    const float* qbase = cq + (size_t)(bn * 16) * 16384;
    const float* kbase = cq + (size_t)(512 + bn * 16) * 16384;

    float acc = 0.f;
    for (int l0 = 0; l0 < 16384; l0 += 128) {
        for (int i = t; i < 16 * 128; i += 256) {
            const int rr = i >> 7;
            const int ll = i & 127;
            qs[rr][ll] = qbase[(size_t)rr * 16384 + l0 + ll];
            ks[rr][ll] = kbase[(size_t)rr * 16384 + l0 + ll];
        }
        __syncthreads();
#pragma unroll 8
        for (int i = 0; i < 128; i++) acc = fmaf(qs[d][i], ks[e][i], acc);
        __syncthreads();
    }
    const int n = bn & 7;
    const float scl = invn[bn * 16 + d] * invn[512 + bn * 16 + e] * temp[n];
    __shared__ float S[16][17];
    S[d][e] = acc * scl;
    __syncthreads();
    if (t < 16) {
        float mm = -1e30f;
#pragma unroll
        for (int e2 = 0; e2 < 16; e2++) mm = fmaxf(mm, S[t][e2]);
        float ex[16];
        float ss = 0.f;
#pragma unroll
        for (int e2 = 0; e2 < 16; e2++) {
            ex[e2] = expf(S[t][e2] - mm);
            ss += ex[e2];
        }
        const float inv = 1.0f / ss;
#pragma unroll
        for (int e2 = 0; e2 < 16; e2++) cattn[(bn * 16 + t) * 16 + e2] = ex[e2] * inv;
    }
}

// ---------------------------------------------------------------------------
// K10: cout = cattn @ cv, written position-major (B, L, 128) into out3
// grid 8192 = (b, n, l/64), block 64
// ---------------------------------------------------------------------------
__global__ void k_cout(const float* __restrict__ cattn, const float* __restrict__ cv,
                       float* __restrict__ out3)
{
    const int blk = blockIdx.x;
    const int bn = blk >> 8;
    const int l0 = (blk & 255) * 64;
    const int t = threadIdx.x;
    __shared__ float A[16][17];
    for (int i = t; i < 256; i += 64) A[i >> 4][i & 15] = cattn[bn * 256 + i];
    __syncthreads();
    const float* vbase = cv + (size_t)(1024 + bn * 16) * 16384;
    float acc[16];
#pragma unroll
    for (int d = 0; d < 16; d++) acc[d] = 0.f;
#pragma unroll
    for (int e = 0; e < 16; e++) {
        const float v = vbase[(size_t)e * 16384 + l0 + t];
#pragma unroll
        for (int d = 0; d < 16; d++) acc[d] = fmaf(A[d][e], v, acc[d]);
    }
    const int b = bn >> 3;
    const int n = bn & 7;
    const size_t orow = ((size_t)b * 16384 + l0 + t) * 128 + n * 16;
#pragma unroll
    for (int d = 0; d < 16; d++) out3[orow + d] = acc[d];
}

// ---------------------------------------------------------------------------
// K11: final projection (B,L,128) @ (128,128) + bias.  grid 1024, block 128
// ---------------------------------------------------------------------------
__global__ void k_proj(const float* __restrict__ out3, const float* __restrict__ pw,
                       const float* __restrict__ pb, float* __restrict__ out)
{
    __shared__ float xs[64 * 128];
    const int p0 = blockIdx.x * 64;
    const int tid = threadIdx.x;
    for (int i = tid; i < 64 * 128; i += 128) xs[i] = out3[(size_t)p0 * 128 + i];
    float wreg[128];
#pragma unroll
    for (int k = 0; k < 128; k++) wreg[k] = pw[k * 128 + tid];
    const float bias = pb[tid];
    __syncthreads();
    for (int p = 0; p < 64; p++) {
        float acc = bias;
        const float* xr = &xs[p * 128];
#pragma unroll
        for (int k = 0; k < 128; k++) acc = fmaf(xr[k], wreg[k], acc);
        out[(size_t)(p0 + p) * 128 + tid] = acc;
    }
}

// ---------------------------------------------------------------------------
extern "C" void kernel_launch(void* const* d_in, const int* in_sizes, int n_in,
                              void* d_out, int out_size, void* d_ws, size_t ws_size,
                              hipStream_t stream)
{
    const float* x       = (const float*)d_in[0];
    const float* wqkv_w  = (const float*)d_in[1];
    const float* wqkv_b  = (const float*)d_in[2];
    const float* bqkv_w  = (const float*)d_in[3];
    const float* bqkv_b  = (const float*)d_in[4];
    const float* lepe_w  = (const float*)d_in[5];
    const float* lepe_b  = (const float*)d_in[6];
    const float* ca_qkv_w = (const float*)d_in[7];
    const float* ca_qkv_b = (const float*)d_in[8];
    const float* ca_temp  = (const float*)d_in[9];
    const float* ca_proj_w = (const float*)d_in[10];
    const float* ca_proj_b = (const float*)d_in[11];

    float* ws = (float*)d_ws;
    float* wqkv = ws;                         // 65536*192 = 12582912 floats
    float* bqkv = ws + 12582912;              // 12582912 floats
    float* cqkv = ws;                         // alias: 25165824 floats (= wqkv+bqkv)
    float* out3 = ws + 25165824;              // 8388608 floats
    float* pq   = out3 + 8388608;             // 65536
    float* pk   = pq + 65536;                 // 65536
    int*   idx  = (int*)(pk + 65536);         // 4096 ints
    float* invn = (float*)idx + 4096;         // 1024
    float* catn = invn + 1024;                // 8192

    k_qkv<<<1024, 384, 0, stream>>>(x, wqkv_w, wqkv_b, bqkv_w, bqkv_b, wqkv, bqkv);
    k_conv<<<65536, 128, 0, stream>>>(wqkv, bqkv, lepe_w, lepe_b, out3);
    k_win<<<8192, 64, 0, stream>>>(wqkv, out3);
    k_pool<<<1024, 64, 0, stream>>>(bqkv, pq, pk);
    k_topk<<<1024, 64, 0, stream>>>(pq, pk, idx);
    k_bra<<<8192, 64, 0, stream>>>(bqkv, idx, out3);
    k_cqkv<<<1024, 384, 0, stream>>>(out3, ca_qkv_w, ca_qkv_b, cqkv);
    k_norm<<<1024, 256, 0, stream>>>(cqkv, invn);
    k_cattn<<<32, 256, 0, stream>>>(cqkv, invn, ca_temp, catn);
    k_cout<<<8192, 64, 0, stream>>>(catn, cqkv, out3);
    k_proj<<<1024, 128, 0, stream>>>(out3, ca_proj_w, ca_proj_b, (float*)d_out);
}

// Round 3
// 1386.192 us; speedup vs baseline: 2.6415x; 2.6415x over previous
//
#include <hip/hip_runtime.h>
#include <math.h>

#define NPOS  65536          // B*H*W
#define LL    16384          // H*W
#define SCALE_F 0.08838834764831843f

// ---------------------------------------------------------------------------
// K1: fused window/bra QKV GEMM.  per position: x[0:64]@wqkv_w, x[64:128]@bqkv_w
// grid 1024, block 384 (one output channel per thread, 64 positions per block)
// ---------------------------------------------------------------------------
__global__ __launch_bounds__(384) void k_qkv(
                      const float* __restrict__ x,
                      const float* __restrict__ ww, const float* __restrict__ wb,
                      const float* __restrict__ bw, const float* __restrict__ bbias,
                      float* __restrict__ wqkv, float* __restrict__ bqkv)
{
    __shared__ float xs[64 * 128];
    const int p0 = blockIdx.x * 64;
    const int tid = threadIdx.x;
    for (int i = tid; i < 64 * 128; i += 384) xs[i] = x[(size_t)p0 * 128 + i];

    const int c = tid;
    float wreg[64];
    float bias;
    int koff;
    if (c < 192) {
#pragma unroll
        for (int k = 0; k < 64; k++) wreg[k] = ww[k * 192 + c];
        bias = wb[c];
        koff = 0;
    } else {
        const int cc = c - 192;
#pragma unroll
        for (int k = 0; k < 64; k++) wreg[k] = bw[k * 192 + cc];
        bias = bbias[cc];
        koff = 64;
    }
    __syncthreads();
    for (int p = 0; p < 64; p++) {
        float acc = bias;
        const float* xr = &xs[p * 128 + koff];
#pragma unroll
        for (int k = 0; k < 64; k++) acc = fmaf(xr[k], wreg[k], acc);
        if (c < 192) wqkv[(size_t)(p0 + p) * 192 + c] = acc;
        else         bqkv[(size_t)(p0 + p) * 192 + (c - 192)] = acc;
    }
}

// ---------------------------------------------------------------------------
// K2: depthwise 3x3 LEPE conv on vcat = [bqkv.v (ch 0..63), wqkv.v (ch 64..127)]
// writes lepe into out3 (B, L, 128).  grid 65536, block 128
// ---------------------------------------------------------------------------
__global__ __launch_bounds__(128) void k_conv(
                       const float* __restrict__ wqkv, const float* __restrict__ bqkv,
                       const float* __restrict__ cw, const float* __restrict__ cb,
                       float* __restrict__ out3)
{
    const int pos = blockIdx.x;
    const int c = threadIdx.x;
    const int b = pos >> 14;
    const int hw = pos & 16383;
    const int h = hw >> 7;
    const int w = hw & 127;
    const float* src = (c < 64) ? (bqkv + 128 + c) : (wqkv + 128 + (c - 64));
    float acc = cb[c];
#pragma unroll
    for (int dh = -1; dh <= 1; dh++) {
        const int h2 = h + dh;
        if (h2 < 0 || h2 >= 128) continue;
#pragma unroll
        for (int dw = -1; dw <= 1; dw++) {
            const int w2 = w + dw;
            if (w2 < 0 || w2 >= 128) continue;
            const size_t row = ((size_t)b * 16384 + h2 * 128 + w2) * 192;
            acc = fmaf(src[row], cw[c * 9 + (dh + 1) * 3 + (dw + 1)], acc);
        }
    }
    out3[(size_t)pos * 128 + c] = acc;
}

// ---------------------------------------------------------------------------
// K3: window attention.  grid 8192 = (b,hr,wr,head), block 64 (query pos)
// adds into out3 channels [0,64)
// ---------------------------------------------------------------------------
__global__ __launch_bounds__(64) void k_win(const float* __restrict__ wqkv,
                                            float* __restrict__ out3)
{
    const int bid = blockIdx.x;
    const int n = bid & 7;
    const int win = bid >> 3;
    const int wr = win & 15;
    const int hr = (win >> 4) & 15;
    const int b = win >> 8;
    const int p = threadIdx.x;
    const int wi = p >> 3, wj = p & 7;
    const int h = hr * 8 + wi, w = wr * 8 + wj;
    const size_t row = ((size_t)b * 16384 + h * 128 + w) * 192;

    __shared__ float kk[64][8];
    __shared__ float vv[64][8];
    float q[8];
#pragma unroll
    for (int d = 0; d < 8; d++) {
        q[d] = wqkv[row + n * 8 + d] * SCALE_F;
        kk[p][d] = wqkv[row + 64 + n * 8 + d];
        vv[p][d] = wqkv[row + 128 + n * 8 + d];
    }
    __syncthreads();

    float s[64];
    float m = -1e30f;
#pragma unroll
    for (int j = 0; j < 64; j++) {
        float a = 0.f;
#pragma unroll
        for (int d = 0; d < 8; d++) a = fmaf(q[d], kk[j][d], a);
        s[j] = a;
        m = fmaxf(m, a);
    }
    float sum = 0.f;
#pragma unroll
    for (int j = 0; j < 64; j++) {
        s[j] = expf(s[j] - m);
        sum += s[j];
    }
    const float inv = 1.0f / sum;
    float o[8] = {0.f, 0.f, 0.f, 0.f, 0.f, 0.f, 0.f, 0.f};
#pragma unroll
    for (int j = 0; j < 64; j++) {
        const float pj = s[j] * inv;
#pragma unroll
        for (int d = 0; d < 8; d++) o[d] = fmaf(pj, vv[j][d], o[d]);
    }
    const size_t orow = ((size_t)b * 16384 + h * 128 + w) * 128;
#pragma unroll
    for (int d = 0; d < 8; d++) out3[orow + n * 8 + d] += o[d];
}

// ---------------------------------------------------------------------------
// K4: 8x8 window mean-pool of bra q and k.  grid 1024 = (b, region), block 64 (ch)
// ---------------------------------------------------------------------------
__global__ __launch_bounds__(64) void k_pool(const float* __restrict__ bqkv,
                       float* __restrict__ pq, float* __restrict__ pk)
{
    const int r = blockIdx.x;
    const int b = r >> 8;
    const int reg = r & 255;
    const int hr = reg >> 4, wr = reg & 15;
    const int c = threadIdx.x;
    float sq = 0.f, sk = 0.f;
    for (int wi = 0; wi < 8; wi++)
        for (int wj = 0; wj < 8; wj++) {
            const size_t row = ((size_t)b * 16384 + (hr * 8 + wi) * 128 + (wr * 8 + wj)) * 192;
            sq += bqkv[row + c];
            sk += bqkv[row + 64 + c];
        }
    pq[(size_t)r * 64 + c] = sq * (1.0f / 64.0f);
    pk[(size_t)r * 64 + c] = sk * (1.0f / 64.0f);
}

// ---------------------------------------------------------------------------
// K5: routing scores + stable top-4.  grid 1024 = (b, i), block 64
// ---------------------------------------------------------------------------
__global__ __launch_bounds__(64) void k_topk(const float* __restrict__ pq,
                       const float* __restrict__ pk, int* __restrict__ idx)
{
    const int bi = blockIdx.x;
    const int b = bi >> 8;
    const int t = threadIdx.x;
    __shared__ float qrow[64];
    __shared__ float s[256];
    qrow[t] = pq[(size_t)bi * 64 + t];
    __syncthreads();
    for (int j4 = 0; j4 < 4; j4++) {
        const int j = j4 * 64 + t;
        const float* krow = pk + ((size_t)b * 256 + j) * 64;
        float a = 0.f;
#pragma unroll
        for (int c = 0; c < 64; c++) a = fmaf(qrow[c], krow[c], a);
        s[j] = a;
    }
    __syncthreads();
    if (t == 0) {
        int chosen[4];
        for (int sel = 0; sel < 4; sel++) {
            float best = -1e30f;
            int bj = -1;
            for (int j = 0; j < 256; j++) {
                bool skip = false;
                for (int u = 0; u < sel; u++) skip = skip || (chosen[u] == j);
                if (!skip && s[j] > best) { best = s[j]; bj = j; }
            }
            chosen[sel] = bj;
            idx[bi * 4 + sel] = bj;
        }
    }
}

// ---------------------------------------------------------------------------
// K6: gathered BRA attention.  grid 8192 = (b, head, region), block 64 (query pos)
// adds into out3 channels [64,128)
// ---------------------------------------------------------------------------
__global__ __launch_bounds__(64) void k_bra(const float* __restrict__ bqkv,
                      const int* __restrict__ idx, float* __restrict__ out3)
{
    const int r = blockIdx.x & 255;
    const int n = (blockIdx.x >> 8) & 7;
    const int b = blockIdx.x >> 11;
    const int p = threadIdx.x;
    const int wi = p >> 3, wj = p & 7;

    __shared__ float kk[256][8];
    __shared__ float vv[256][8];
    __shared__ int regs[4];
    if (p < 4) regs[p] = idx[((b << 8) + r) * 4 + p];
    __syncthreads();

    for (int t = 0; t < 4; t++) {
        const int rt = regs[t];
        const int hr = rt >> 4, wr2 = rt & 15;
        const size_t row = ((size_t)b * 16384 + (hr * 8 + wi) * 128 + (wr2 * 8 + wj)) * 192;
#pragma unroll
        for (int d = 0; d < 8; d++) {
            kk[t * 64 + p][d] = bqkv[row + 64 + n * 8 + d];
            vv[t * 64 + p][d] = bqkv[row + 128 + n * 8 + d];
        }
    }
    const int hq = (r >> 4) * 8 + wi, wq = (r & 15) * 8 + wj;
    const size_t qoff = ((size_t)b * 16384 + hq * 128 + wq) * 192;
    float q[8];
#pragma unroll
    for (int d = 0; d < 8; d++) q[d] = bqkv[qoff + n * 8 + d] * SCALE_F;
    __syncthreads();

    float m = -1e30f;
    for (int j = 0; j < 256; j++) {
        float a = 0.f;
#pragma unroll
        for (int d = 0; d < 8; d++) a = fmaf(q[d], kk[j][d], a);
        m = fmaxf(m, a);
    }
    float sum = 0.f;
    float o[8] = {0.f, 0.f, 0.f, 0.f, 0.f, 0.f, 0.f, 0.f};
    for (int j = 0; j < 256; j++) {
        float a = 0.f;
#pragma unroll
        for (int d = 0; d < 8; d++) a = fmaf(q[d], kk[j][d], a);
        const float e = expf(a - m);
        sum += e;
#pragma unroll
        for (int d = 0; d < 8; d++) o[d] = fmaf(e, vv[j][d], o[d]);
    }
    const float inv = 1.0f / sum;
    const size_t orow = ((size_t)b * 16384 + hq * 128 + wq) * 128;
#pragma unroll
    for (int d = 0; d < 8; d++) out3[orow + 64 + n * 8 + d] += o[d] * inv;
}

// ---------------------------------------------------------------------------
// K7: channel-attn QKV GEMM, output transposed to (3, B, NH, 16, L)
// grid 1024, block 384
// ---------------------------------------------------------------------------
__global__ __launch_bounds__(384) void k_cqkv(
                       const float* __restrict__ out3, const float* __restrict__ qw,
                       const float* __restrict__ qb, float* __restrict__ cq)
{
    __shared__ float xs[64 * 128];
    const int p0 = blockIdx.x * 64;
    const int tid = threadIdx.x;
    for (int i = tid; i < 64 * 128; i += 384) xs[i] = out3[(size_t)p0 * 128 + i];

    const int c = tid;
    float wreg[128];
#pragma unroll
    for (int k = 0; k < 128; k++) wreg[k] = qw[k * 384 + c];
    const float bias = qb[c];
    const int s = c >> 7;
    const int cc = c & 127;
    const int n = cc >> 4;
    const int d = cc & 15;
    __syncthreads();
    for (int p = 0; p < 64; p++) {
        float acc = bias;
        const float* xr = &xs[p * 128];
#pragma unroll
        for (int k = 0; k < 128; k++) acc = fmaf(xr[k], wreg[k], acc);
        const int P = p0 + p;
        const int b = P >> 14;
        const int l = P & 16383;
        cq[((((size_t)s * 4 + b) * 8 + n) * 16 + d) * 16384 + l] = acc;
    }
}

// ---------------------------------------------------------------------------
// K8: L2 norms of cq, ck rows.  grid 1024 rows (q rows 0..511, k rows 512..1023)
// ---------------------------------------------------------------------------
__global__ __launch_bounds__(256) void k_norm(const float* __restrict__ cq,
                                              float* __restrict__ invn)
{
    __shared__ float red[256];
    const int row = blockIdx.x;
    const int t = threadIdx.x;
    const float* xr = cq + (size_t)row * 16384;
    float acc = 0.f;
    for (int i = t; i < 16384; i += 256) {
        const float v = xr[i];
        acc = fmaf(v, v, acc);
    }
    red[t] = acc;
    __syncthreads();
    for (int off = 128; off > 0; off >>= 1) {
        if (t < off) red[t] += red[t + off];
        __syncthreads();
    }
    if (t == 0) invn[row] = 1.0f / fmaxf(sqrtf(red[0]), 1e-12f);
}

// ---------------------------------------------------------------------------
// K9a: channel attention partial Gram.  grid 512 = (bn, chunk), block 256 = (d, e)
// each block covers an L-chunk of 1024
// ---------------------------------------------------------------------------
__global__ __launch_bounds__(256) void k_cattn_part(const float* __restrict__ cq,
                                                    float* __restrict__ part)
{
    const int bn = blockIdx.x >> 4;
    const int ch = blockIdx.x & 15;
    const int t = threadIdx.x;
    const int d = t >> 4;
    const int e = t & 15;
    __shared__ float qs[16][132];
    __shared__ float ks[16][132];
    const float* qbase = cq + (size_t)(bn * 16) * 16384 + ch * 1024;
    const float* kbase = cq + (size_t)(512 + bn * 16) * 16384 + ch * 1024;

    float acc = 0.f;
    for (int l0 = 0; l0 < 1024; l0 += 128) {
        for (int i = t; i < 16 * 128; i += 256) {
            const int rr = i >> 7;
            const int ll = i & 127;
            qs[rr][ll] = qbase[(size_t)rr * 16384 + l0 + ll];
            ks[rr][ll] = kbase[(size_t)rr * 16384 + l0 + ll];
        }
        __syncthreads();
#pragma unroll 8
        for (int i = 0; i < 128; i++) acc = fmaf(qs[d][i], ks[e][i], acc);
        __syncthreads();
    }
    part[((size_t)bn * 16 + ch) * 256 + t] = acc;
}

// ---------------------------------------------------------------------------
// K9b: reduce partials + scale + softmax.  grid 32 = (b, n), block 256
// ---------------------------------------------------------------------------
__global__ __launch_bounds__(256) void k_cattn_red(const float* __restrict__ part,
                        const float* __restrict__ invn,
                        const float* __restrict__ temp, float* __restrict__ cattn)
{
    const int bn = blockIdx.x;
    const int t = threadIdx.x;
    const int d = t >> 4;
    const int e = t & 15;
    float acc = 0.f;
#pragma unroll
    for (int ch = 0; ch < 16; ch++) acc += part[((size_t)bn * 16 + ch) * 256 + t];
    const int n = bn & 7;
    const float scl = invn[bn * 16 + d] * invn[512 + bn * 16 + e] * temp[n];
    __shared__ float S[16][17];
    S[d][e] = acc * scl;
    __syncthreads();
    if (t < 16) {
        float mm = -1e30f;
#pragma unroll
        for (int e2 = 0; e2 < 16; e2++) mm = fmaxf(mm, S[t][e2]);
        float ex[16];
        float ss = 0.f;
#pragma unroll
        for (int e2 = 0; e2 < 16; e2++) {
            ex[e2] = expf(S[t][e2] - mm);
            ss += ex[e2];
        }
        const float inv = 1.0f / ss;
#pragma unroll
        for (int e2 = 0; e2 < 16; e2++) cattn[(bn * 16 + t) * 16 + e2] = ex[e2] * inv;
    }
}

// ---------------------------------------------------------------------------
// K10: cout = cattn @ cv, written position-major (B, L, 128) into out3
// grid 8192 = (b, n, l/64), block 64
// ---------------------------------------------------------------------------
__global__ __launch_bounds__(64) void k_cout(const float* __restrict__ cattn,
                       const float* __restrict__ cv, float* __restrict__ out3)
{
    const int blk = blockIdx.x;
    const int bn = blk >> 8;
    const int l0 = (blk & 255) * 64;
    const int t = threadIdx.x;
    __shared__ float A[16][17];
    for (int i = t; i < 256; i += 64) A[i >> 4][i & 15] = cattn[bn * 256 + i];
    __syncthreads();
    const float* vbase = cv + (size_t)(1024 + bn * 16) * 16384;
    float acc[16];
#pragma unroll
    for (int d = 0; d < 16; d++) acc[d] = 0.f;
#pragma unroll
    for (int e = 0; e < 16; e++) {
        const float v = vbase[(size_t)e * 16384 + l0 + t];
#pragma unroll
        for (int d = 0; d < 16; d++) acc[d] = fmaf(A[d][e], v, acc[d]);
    }
    const int b = bn >> 3;
    const int n = bn & 7;
    const size_t orow = ((size_t)b * 16384 + l0 + t) * 128 + n * 16;
#pragma unroll
    for (int d = 0; d < 16; d++) out3[orow + d] = acc[d];
}

// ---------------------------------------------------------------------------
// K11: final projection (B,L,128) @ (128,128) + bias.  grid 1024, block 128
// ---------------------------------------------------------------------------
__global__ __launch_bounds__(128) void k_proj(
                       const float* __restrict__ out3, const float* __restrict__ pw,
                       const float* __restrict__ pb, float* __restrict__ out)
{
    __shared__ float xs[64 * 128];
    const int p0 = blockIdx.x * 64;
    const int tid = threadIdx.x;
    for (int i = tid; i < 64 * 128; i += 128) xs[i] = out3[(size_t)p0 * 128 + i];
    float wreg[128];
#pragma unroll
    for (int k = 0; k < 128; k++) wreg[k] = pw[k * 128 + tid];
    const float bias = pb[tid];
    __syncthreads();
    for (int p = 0; p < 64; p++) {
        float acc = bias;
        const float* xr = &xs[p * 128];
#pragma unroll
        for (int k = 0; k < 128; k++) acc = fmaf(xr[k], wreg[k], acc);
        out[(size_t)(p0 + p) * 128 + tid] = acc;
    }
}

// ---------------------------------------------------------------------------
extern "C" void kernel_launch(void* const* d_in, const int* in_sizes, int n_in,
                              void* d_out, int out_size, void* d_ws, size_t ws_size,
                              hipStream_t stream)
{
    const float* x       = (const float*)d_in[0];
    const float* wqkv_w  = (const float*)d_in[1];
    const float* wqkv_b  = (const float*)d_in[2];
    const float* bqkv_w  = (const float*)d_in[3];
    const float* bqkv_b  = (const float*)d_in[4];
    const float* lepe_w  = (const float*)d_in[5];
    const float* lepe_b  = (const float*)d_in[6];
    const float* ca_qkv_w = (const float*)d_in[7];
    const float* ca_qkv_b = (const float*)d_in[8];
    const float* ca_temp  = (const float*)d_in[9];
    const float* ca_proj_w = (const float*)d_in[10];
    const float* ca_proj_b = (const float*)d_in[11];

    float* ws = (float*)d_ws;
    float* wqkv = ws;                         // 65536*192 = 12582912 floats
    float* bqkv = ws + 12582912;              // 12582912 floats
    float* cqkv = ws;                         // alias: 25165824 floats (= wqkv+bqkv)
    float* out3 = ws + 25165824;              // 8388608 floats
    float* pq   = out3 + 8388608;             // 65536
    float* pk   = pq + 65536;                 // 65536
    float* part = pq;                         // alias pq+pk (dead after k_topk): 131072
    int*   idx  = (int*)(pk + 65536);         // 4096 ints
    float* invn = (float*)idx + 4096;         // 1024
    float* catn = invn + 1024;                // 8192

    k_qkv<<<1024, 384, 0, stream>>>(x, wqkv_w, wqkv_b, bqkv_w, bqkv_b, wqkv, bqkv);
    k_conv<<<65536, 128, 0, stream>>>(wqkv, bqkv, lepe_w, lepe_b, out3);
    k_win<<<8192, 64, 0, stream>>>(wqkv, out3);
    k_pool<<<1024, 64, 0, stream>>>(bqkv, pq, pk);
    k_topk<<<1024, 64, 0, stream>>>(pq, pk, idx);
    k_bra<<<8192, 64, 0, stream>>>(bqkv, idx, out3);
    k_cqkv<<<1024, 384, 0, stream>>>(out3, ca_qkv_w, ca_qkv_b, cqkv);
    k_norm<<<1024, 256, 0, stream>>>(cqkv, invn);
    k_cattn_part<<<512, 256, 0, stream>>>(cqkv, part);
    k_cattn_red<<<32, 256, 0, stream>>>(part, invn, ca_temp, catn);
    k_cout<<<8192, 64, 0, stream>>>(catn, cqkv, out3);
    k_proj<<<1024, 128, 0, stream>>>(out3, ca_proj_w, ca_proj_b, (float*)d_out);
}

// Round 4
// 1298.398 us; speedup vs baseline: 2.8201x; 1.0676x over previous
//
#include <hip/hip_runtime.h>
#include <math.h>

#define SCALE_F 0.08838834764831843f

// ---------------------------------------------------------------------------
// K1: fused window/bra QKV GEMM.  per position: x[0:64]@wqkv_w, x[64:128]@bqkv_w
// grid 1024, block 384 (one output channel per thread, 64 positions per block)
// ---------------------------------------------------------------------------
__global__ __launch_bounds__(384) void k_qkv(
                      const float* __restrict__ x,
                      const float* __restrict__ ww, const float* __restrict__ wb,
                      const float* __restrict__ bw, const float* __restrict__ bbias,
                      float* __restrict__ wqkv, float* __restrict__ bqkv)
{
    __shared__ float xs[64 * 128];
    const int p0 = blockIdx.x * 64;
    const int tid = threadIdx.x;
    for (int i = tid; i < 64 * 128; i += 384) xs[i] = x[(size_t)p0 * 128 + i];

    const int c = tid;
    float wreg[64];
    float bias;
    int koff;
    if (c < 192) {
#pragma unroll
        for (int k = 0; k < 64; k++) wreg[k] = ww[k * 192 + c];
        bias = wb[c];
        koff = 0;
    } else {
        const int cc = c - 192;
#pragma unroll
        for (int k = 0; k < 64; k++) wreg[k] = bw[k * 192 + cc];
        bias = bbias[cc];
        koff = 64;
    }
    __syncthreads();
    for (int p = 0; p < 64; p++) {
        float acc = bias;
        const float* xr = &xs[p * 128 + koff];
#pragma unroll
        for (int k = 0; k < 64; k++) acc = fmaf(xr[k], wreg[k], acc);
        if (c < 192) wqkv[(size_t)(p0 + p) * 192 + c] = acc;
        else         bqkv[(size_t)(p0 + p) * 192 + (c - 192)] = acc;
    }
}

// ---------------------------------------------------------------------------
// K2: depthwise 3x3 LEPE conv on vcat = [bqkv.v (ch 0..63), wqkv.v (ch 64..127)]
// writes lepe into out3 (B, L, 128).  grid 65536, block 128
// ---------------------------------------------------------------------------
__global__ __launch_bounds__(128) void k_conv(
                       const float* __restrict__ wqkv, const float* __restrict__ bqkv,
                       const float* __restrict__ cw, const float* __restrict__ cb,
                       float* __restrict__ out3)
{
    const int pos = blockIdx.x;
    const int c = threadIdx.x;
    const int b = pos >> 14;
    const int hw = pos & 16383;
    const int h = hw >> 7;
    const int w = hw & 127;
    const float* src = (c < 64) ? (bqkv + 128 + c) : (wqkv + 128 + (c - 64));
    float acc = cb[c];
#pragma unroll
    for (int dh = -1; dh <= 1; dh++) {
        const int h2 = h + dh;
        if (h2 < 0 || h2 >= 128) continue;
#pragma unroll
        for (int dw = -1; dw <= 1; dw++) {
            const int w2 = w + dw;
            if (w2 < 0 || w2 >= 128) continue;
            const size_t row = ((size_t)b * 16384 + h2 * 128 + w2) * 192;
            acc = fmaf(src[row], cw[c * 9 + (dh + 1) * 3 + (dw + 1)], acc);
        }
    }
    out3[(size_t)pos * 128 + c] = acc;
}

// ---------------------------------------------------------------------------
// K3: window attention.  grid 8192 = (b,hr,wr,head), block 64 (query pos)
// adds into out3 channels [0,64)
// ---------------------------------------------------------------------------
__global__ __launch_bounds__(64) void k_win(const float* __restrict__ wqkv,
                                            float* __restrict__ out3)
{
    const int bid = blockIdx.x;
    const int n = bid & 7;
    const int win = bid >> 3;
    const int wr = win & 15;
    const int hr = (win >> 4) & 15;
    const int b = win >> 8;
    const int p = threadIdx.x;
    const int wi = p >> 3, wj = p & 7;
    const int h = hr * 8 + wi, w = wr * 8 + wj;
    const size_t row = ((size_t)b * 16384 + h * 128 + w) * 192;

    __shared__ float kk[64][8];
    __shared__ float vv[64][8];
    float q[8];
#pragma unroll
    for (int d = 0; d < 8; d++) {
        q[d] = wqkv[row + n * 8 + d] * SCALE_F;
        kk[p][d] = wqkv[row + 64 + n * 8 + d];
        vv[p][d] = wqkv[row + 128 + n * 8 + d];
    }
    __syncthreads();

    float s[64];
    float m = -1e30f;
#pragma unroll
    for (int j = 0; j < 64; j++) {
        float a = 0.f;
#pragma unroll
        for (int d = 0; d < 8; d++) a = fmaf(q[d], kk[j][d], a);
        s[j] = a;
        m = fmaxf(m, a);
    }
    float sum = 0.f;
#pragma unroll
    for (int j = 0; j < 64; j++) {
        s[j] = expf(s[j] - m);
        sum += s[j];
    }
    const float inv = 1.0f / sum;
    float o[8] = {0.f, 0.f, 0.f, 0.f, 0.f, 0.f, 0.f, 0.f};
#pragma unroll
    for (int j = 0; j < 64; j++) {
        const float pj = s[j] * inv;
#pragma unroll
        for (int d = 0; d < 8; d++) o[d] = fmaf(pj, vv[j][d], o[d]);
    }
    const size_t orow = ((size_t)b * 16384 + h * 128 + w) * 128;
#pragma unroll
    for (int d = 0; d < 8; d++) out3[orow + n * 8 + d] += o[d];
}

// ---------------------------------------------------------------------------
// K4: 8x8 window mean-pool of bra q and k.  grid 1024 = (b, region), block 64 (ch)
// ---------------------------------------------------------------------------
__global__ __launch_bounds__(64) void k_pool(const float* __restrict__ bqkv,
                       float* __restrict__ pq, float* __restrict__ pk)
{
    const int r = blockIdx.x;
    const int b = r >> 8;
    const int reg = r & 255;
    const int hr = reg >> 4, wr = reg & 15;
    const int c = threadIdx.x;
    float sq = 0.f, sk = 0.f;
    for (int wi = 0; wi < 8; wi++)
        for (int wj = 0; wj < 8; wj++) {
            const size_t row = ((size_t)b * 16384 + (hr * 8 + wi) * 128 + (wr * 8 + wj)) * 192;
            sq += bqkv[row + c];
            sk += bqkv[row + 64 + c];
        }
    pq[(size_t)r * 64 + c] = sq * (1.0f / 64.0f);
    pk[(size_t)r * 64 + c] = sk * (1.0f / 64.0f);
}

// ---------------------------------------------------------------------------
// K5: routing scores + stable top-4.  grid 1024 = (b, i), block 64
// ---------------------------------------------------------------------------
__global__ __launch_bounds__(64) void k_topk(const float* __restrict__ pq,
                       const float* __restrict__ pk, int* __restrict__ idx)
{
    const int bi = blockIdx.x;
    const int b = bi >> 8;
    const int t = threadIdx.x;
    __shared__ float qrow[64];
    __shared__ float s[256];
    qrow[t] = pq[(size_t)bi * 64 + t];
    __syncthreads();
    for (int j4 = 0; j4 < 4; j4++) {
        const int j = j4 * 64 + t;
        const float* krow = pk + ((size_t)b * 256 + j) * 64;
        float a = 0.f;
#pragma unroll
        for (int c = 0; c < 64; c++) a = fmaf(qrow[c], krow[c], a);
        s[j] = a;
    }
    __syncthreads();
    if (t == 0) {
        int chosen[4];
        for (int sel = 0; sel < 4; sel++) {
            float best = -1e30f;
            int bj = -1;
            for (int j = 0; j < 256; j++) {
                bool skip = false;
                for (int u = 0; u < sel; u++) skip = skip || (chosen[u] == j);
                if (!skip && s[j] > best) { best = s[j]; bj = j; }
            }
            chosen[sel] = bj;
            idx[bi * 4 + sel] = bj;
        }
    }
}

// ---------------------------------------------------------------------------
// K6: gathered BRA attention.  grid 8192 = (b, head, region), block 64 (query pos)
// adds into out3 channels [64,128)
// ---------------------------------------------------------------------------
__global__ __launch_bounds__(64) void k_bra(const float* __restrict__ bqkv,
                      const int* __restrict__ idx, float* __restrict__ out3)
{
    const int r = blockIdx.x & 255;
    const int n = (blockIdx.x >> 8) & 7;
    const int b = blockIdx.x >> 11;
    const int p = threadIdx.x;
    const int wi = p >> 3, wj = p & 7;

    __shared__ float kk[256][8];
    __shared__ float vv[256][8];
    __shared__ int regs[4];
    if (p < 4) regs[p] = idx[((b << 8) + r) * 4 + p];
    __syncthreads();

    for (int t = 0; t < 4; t++) {
        const int rt = regs[t];
        const int hr = rt >> 4, wr2 = rt & 15;
        const size_t row = ((size_t)b * 16384 + (hr * 8 + wi) * 128 + (wr2 * 8 + wj)) * 192;
#pragma unroll
        for (int d = 0; d < 8; d++) {
            kk[t * 64 + p][d] = bqkv[row + 64 + n * 8 + d];
            vv[t * 64 + p][d] = bqkv[row + 128 + n * 8 + d];
        }
    }
    const int hq = (r >> 4) * 8 + wi, wq = (r & 15) * 8 + wj;
    const size_t qoff = ((size_t)b * 16384 + hq * 128 + wq) * 192;
    float q[8];
#pragma unroll
    for (int d = 0; d < 8; d++) q[d] = bqkv[qoff + n * 8 + d] * SCALE_F;
    __syncthreads();

    float m = -1e30f;
    for (int j = 0; j < 256; j++) {
        float a = 0.f;
#pragma unroll
        for (int d = 0; d < 8; d++) a = fmaf(q[d], kk[j][d], a);
        m = fmaxf(m, a);
    }
    float sum = 0.f;
    float o[8] = {0.f, 0.f, 0.f, 0.f, 0.f, 0.f, 0.f, 0.f};
    for (int j = 0; j < 256; j++) {
        float a = 0.f;
#pragma unroll
        for (int d = 0; d < 8; d++) a = fmaf(q[d], kk[j][d], a);
        const float e = expf(a - m);
        sum += e;
#pragma unroll
        for (int d = 0; d < 8; d++) o[d] = fmaf(e, vv[j][d], o[d]);
    }
    const float inv = 1.0f / sum;
    const size_t orow = ((size_t)b * 16384 + hq * 128 + wq) * 128;
#pragma unroll
    for (int d = 0; d < 8; d++) out3[orow + 64 + n * 8 + d] += o[d] * inv;
}

// ---------------------------------------------------------------------------
// K7: channel-attn QKV GEMM, POSITION-MAJOR output (B*L, 384).
// channel layout within row: s*128 + n*16 + d  (s=0 q, 1 k, 2 v)
// grid 1024, block 384.  Coalesced 1536B row writes.
// ---------------------------------------------------------------------------
__global__ __launch_bounds__(384, 2) void k_cqkv(
                       const float* __restrict__ out3, const float* __restrict__ qw,
                       const float* __restrict__ qb, float* __restrict__ cq)
{
    __shared__ float xs[64 * 128];
    const int p0 = blockIdx.x * 64;
    const int tid = threadIdx.x;
    for (int i = tid; i < 64 * 128; i += 384) xs[i] = out3[(size_t)p0 * 128 + i];

    const int c = tid;
    float wreg[128];
#pragma unroll
    for (int k = 0; k < 128; k++) wreg[k] = qw[k * 384 + c];
    const float bias = qb[c];
    __syncthreads();
    for (int p = 0; p < 64; p++) {
        float acc = bias;
        const float* xr = &xs[p * 128];
#pragma unroll
        for (int k = 0; k < 128; k++) acc = fmaf(xr[k], wreg[k], acc);
        cq[(size_t)(p0 + p) * 384 + c] = acc;
    }
}

// ---------------------------------------------------------------------------
// K9a: channel-attn partial Gram + partial sq-norms.  grid 512 = (bn, chunk),
// block 256 = (d, e).  Reads position-major cq; each block covers 1024 positions.
// part row (per (bn,chunk)): [0,256) gram, [256,272) q-norm, [272,288) k-norm
// ---------------------------------------------------------------------------
__global__ __launch_bounds__(256) void k_cattn_part(const float* __restrict__ cq,
                                                    float* __restrict__ part)
{
    const int bn = blockIdx.x >> 4;      // b*8+n
    const int ch = blockIdx.x & 15;
    const int b = bn >> 3, n = bn & 7;
    const int t = threadIdx.x;
    const int d = t >> 4, e = t & 15;
    __shared__ float qs[128][16];
    __shared__ float ks[128][16];
    const float* base = cq + ((size_t)b * 16384 + ch * 1024) * 384;

    float acc = 0.f, nq = 0.f, nk = 0.f;
    for (int l0 = 0; l0 < 1024; l0 += 128) {
        for (int i = t; i < 128 * 32; i += 256) {
            const int pos = i >> 5;
            const int en = i & 31;
            const int col = (en < 16) ? (n * 16 + en) : (128 + n * 16 + en - 16);
            const float v = base[(size_t)(l0 + pos) * 384 + col];
            if (en < 16) qs[pos][en] = v;
            else         ks[pos][en - 16] = v;
        }
        __syncthreads();
#pragma unroll
        for (int l = 0; l < 128; l++) acc = fmaf(qs[l][d], ks[l][e], acc);
        // partial sq-norms: q-channel d over l==e (mod 16), k-channel e over l==d (mod 16)
#pragma unroll
        for (int l8 = 0; l8 < 8; l8++) {
            const float qv = qs[l8 * 16 + e][d];
            const float kv = ks[l8 * 16 + d][e];
            nq = fmaf(qv, qv, nq);
            nk = fmaf(kv, kv, nk);
        }
        __syncthreads();
    }
    part[((size_t)bn * 16 + ch) * 288 + t] = acc;

    __shared__ float rq[16][17];
    __shared__ float rk[16][17];
    rq[d][e] = nq;     // q-channel d, partition e
    rk[e][d] = nk;     // k-channel e, partition d
    __syncthreads();
    if (t < 16) {
        float sq = 0.f, sk = 0.f;
#pragma unroll
        for (int j = 0; j < 16; j++) { sq += rq[t][j]; sk += rk[t][j]; }
        part[((size_t)bn * 16 + ch) * 288 + 256 + t] = sq;
        part[((size_t)bn * 16 + ch) * 288 + 272 + t] = sk;
    }
}

// ---------------------------------------------------------------------------
// K9b: reduce partials, build inv-norms, scale, softmax.  grid 32 = bn, block 256
// ---------------------------------------------------------------------------
__global__ __launch_bounds__(256) void k_cattn_red(const float* __restrict__ part,
                        const float* __restrict__ temp, float* __restrict__ cattn)
{
    const int bn = blockIdx.x;
    const int t = threadIdx.x;
    const int d = t >> 4;
    const int e = t & 15;
    float acc = 0.f;
#pragma unroll
    for (int ch = 0; ch < 16; ch++) acc += part[((size_t)bn * 16 + ch) * 288 + t];
    __shared__ float inorm[32];
    if (t < 32) {
        float s = 0.f;
#pragma unroll
        for (int ch = 0; ch < 16; ch++) s += part[((size_t)bn * 16 + ch) * 288 + 256 + t];
        inorm[t] = 1.0f / fmaxf(sqrtf(s), 1e-12f);
    }
    __syncthreads();
    const int n = bn & 7;
    const float scl = inorm[d] * inorm[16 + e] * temp[n];
    __shared__ float S[16][17];
    S[d][e] = acc * scl;
    __syncthreads();
    if (t < 16) {
        float mm = -1e30f;
#pragma unroll
        for (int e2 = 0; e2 < 16; e2++) mm = fmaxf(mm, S[t][e2]);
        float ex[16];
        float ss = 0.f;
#pragma unroll
        for (int e2 = 0; e2 < 16; e2++) {
            ex[e2] = expf(S[t][e2] - mm);
            ss += ex[e2];
        }
        const float inv = 1.0f / ss;
#pragma unroll
        for (int e2 = 0; e2 < 16; e2++) cattn[(bn * 16 + t) * 16 + e2] = ex[e2] * inv;
    }
}

// ---------------------------------------------------------------------------
// K10: cout = cattn @ cv (position-major cv), written (B, L, 128) into out3
// grid 8192 = (bn, l/64), block 64
// ---------------------------------------------------------------------------
__global__ __launch_bounds__(64) void k_cout(const float* __restrict__ cattn,
                       const float* __restrict__ cq, float* __restrict__ out3)
{
    const int blk = blockIdx.x;
    const int bn = blk >> 8;
    const int b = bn >> 3, n = bn & 7;
    const int l0 = (blk & 255) * 64;
    const int t = threadIdx.x;
    __shared__ float A[16][17];
    for (int i = t; i < 256; i += 64) A[i >> 4][i & 15] = cattn[bn * 256 + i];
    __syncthreads();
    const int pos = l0 + t;
    const float* vp = cq + ((size_t)b * 16384 + pos) * 384 + 256 + n * 16;
    float v[16];
#pragma unroll
    for (int e4 = 0; e4 < 4; e4++) {
        const float4 f = ((const float4*)vp)[e4];
        v[e4 * 4 + 0] = f.x; v[e4 * 4 + 1] = f.y; v[e4 * 4 + 2] = f.z; v[e4 * 4 + 3] = f.w;
    }
    float acc[16];
#pragma unroll
    for (int d = 0; d < 16; d++) acc[d] = 0.f;
#pragma unroll
    for (int e = 0; e < 16; e++) {
#pragma unroll
        for (int d = 0; d < 16; d++) acc[d] = fmaf(A[d][e], v[e], acc[d]);
    }
    float* op = out3 + ((size_t)b * 16384 + pos) * 128 + n * 16;
#pragma unroll
    for (int d4 = 0; d4 < 4; d4++) {
        float4 f;
        f.x = acc[d4 * 4 + 0]; f.y = acc[d4 * 4 + 1]; f.z = acc[d4 * 4 + 2]; f.w = acc[d4 * 4 + 3];
        ((float4*)op)[d4] = f;
    }
}

// ---------------------------------------------------------------------------
// K11: final projection (B,L,128) @ (128,128) + bias.  grid 1024, block 128
// ---------------------------------------------------------------------------
__global__ __launch_bounds__(128, 2) void k_proj(
                       const float* __restrict__ out3, const float* __restrict__ pw,
                       const float* __restrict__ pb, float* __restrict__ out)
{
    __shared__ float xs[64 * 128];
    const int p0 = blockIdx.x * 64;
    const int tid = threadIdx.x;
    for (int i = tid; i < 64 * 128; i += 128) xs[i] = out3[(size_t)p0 * 128 + i];
    float wreg[128];
#pragma unroll
    for (int k = 0; k < 128; k++) wreg[k] = pw[k * 128 + tid];
    const float bias = pb[tid];
    __syncthreads();
    for (int p = 0; p < 64; p++) {
        float acc = bias;
        const float* xr = &xs[p * 128];
#pragma unroll
        for (int k = 0; k < 128; k++) acc = fmaf(xr[k], wreg[k], acc);
        out[(size_t)(p0 + p) * 128 + tid] = acc;
    }
}

// ---------------------------------------------------------------------------
extern "C" void kernel_launch(void* const* d_in, const int* in_sizes, int n_in,
                              void* d_out, int out_size, void* d_ws, size_t ws_size,
                              hipStream_t stream)
{
    const float* x       = (const float*)d_in[0];
    const float* wqkv_w  = (const float*)d_in[1];
    const float* wqkv_b  = (const float*)d_in[2];
    const float* bqkv_w  = (const float*)d_in[3];
    const float* bqkv_b  = (const float*)d_in[4];
    const float* lepe_w  = (const float*)d_in[5];
    const float* lepe_b  = (const float*)d_in[6];
    const float* ca_qkv_w = (const float*)d_in[7];
    const float* ca_qkv_b = (const float*)d_in[8];
    const float* ca_temp  = (const float*)d_in[9];
    const float* ca_proj_w = (const float*)d_in[10];
    const float* ca_proj_b = (const float*)d_in[11];

    float* ws = (float*)d_ws;
    float* wqkv = ws;                         // 65536*192 floats
    float* bqkv = ws + 12582912;              // 65536*192 floats
    float* cqkv = ws;                         // alias wqkv+bqkv: 65536*384 floats
    float* out3 = ws + 25165824;              // 65536*128 floats
    float* pq   = out3 + 8388608;             // 65536 (dead after k_topk)
    float* pk   = pq + 65536;                 // 65536 (dead after k_topk)
    int*   idx  = (int*)(pk + 65536);         // 4096 ints (dead after k_bra)
    float* part = pq;                         // alias pq+pk+idx: 32*16*288 = 147456
    float* catn = pq + 147456;                // 8192

    k_qkv<<<1024, 384, 0, stream>>>(x, wqkv_w, wqkv_b, bqkv_w, bqkv_b, wqkv, bqkv);
    k_conv<<<65536, 128, 0, stream>>>(wqkv, bqkv, lepe_w, lepe_b, out3);
    k_win<<<8192, 64, 0, stream>>>(wqkv, out3);
    k_pool<<<1024, 64, 0, stream>>>(bqkv, pq, pk);
    k_topk<<<1024, 64, 0, stream>>>(pq, pk, idx);
    k_bra<<<8192, 64, 0, stream>>>(bqkv, idx, out3);
    k_cqkv<<<1024, 384, 0, stream>>>(out3, ca_qkv_w, ca_qkv_b, cqkv);
    k_cattn_part<<<512, 256, 0, stream>>>(cqkv, part);
    k_cattn_red<<<32, 256, 0, stream>>>(part, ca_temp, catn);
    k_cout<<<8192, 64, 0, stream>>>(catn, cqkv, out3);
    k_proj<<<1024, 128, 0, stream>>>(out3, ca_proj_w, ca_proj_b, (float*)d_out);
}

// Round 8
// 695.818 us; speedup vs baseline: 5.2622x; 1.8660x over previous
//
#include <hip/hip_runtime.h>
#include <math.h>

#define SCALE_F 0.08838834764831843f

typedef __attribute__((ext_vector_type(8))) short short8;
typedef __attribute__((ext_vector_type(4))) float f32x4;

__device__ __forceinline__ ushort f2bf(float f) {
    unsigned u = __float_as_uint(f);
    u = (u + 0x7fff + ((u >> 16) & 1)) >> 16;   // RNE
    return (ushort)u;
}
__device__ __forceinline__ float b2f(ushort h) {
    return __uint_as_float(((unsigned)h) << 16);
}

// ---------------------------------------------------------------------------
// K0: pack weights to bf16 hi/lo pairs, transposed to (N,128) k-contiguous.
// wt1 (384x128): block-diag [ww | 0 ; 0 | bw].  wt2 (384x128) = ca_qkv_w^T.
// wt3 (128x128) = ca_proj_w^T.  grid 896, block 128.
// ---------------------------------------------------------------------------
__global__ __launch_bounds__(128) void k_pack(
    const float* __restrict__ ww, const float* __restrict__ bw,
    const float* __restrict__ qw, const float* __restrict__ pw,
    ushort* __restrict__ wt1h, ushort* __restrict__ wt1l,
    ushort* __restrict__ wt2h, ushort* __restrict__ wt2l,
    ushort* __restrict__ wt3h, ushort* __restrict__ wt3l)
{
    const int blk = blockIdx.x;
    const int t = threadIdx.x;
    float v;
    ushort *dh, *dl;
    int off;
    if (blk < 384) {
        const int n = blk;
        if (n < 192) v = (t < 64) ? ww[t * 192 + n] : 0.f;
        else         v = (t >= 64) ? bw[(t - 64) * 192 + (n - 192)] : 0.f;
        dh = wt1h; dl = wt1l; off = n * 128 + t;
    } else if (blk < 768) {
        const int n = blk - 384;
        v = qw[t * 384 + n];
        dh = wt2h; dl = wt2l; off = n * 128 + t;
    } else {
        const int n = blk - 768;
        v = pw[t * 128 + n];
        dh = wt3h; dl = wt3l; off = n * 128 + t;
    }
    const ushort h = f2bf(v);
    dh[off] = h;
    dl[off] = f2bf(v - b2f(h));
}

// ---------------------------------------------------------------------------
// K-GEMM (split precision): C = A(M x 128 fp32) @ W^T + bias computed as
// ah*bh + ah*bl + al*bh in bf16 MFMA (fp32-accurate to ~4e-6 rel).
// A-tile M=64 staged hi/lo in LDS; B hi/lo frags from global (L2-hot).
// block 256 (4 waves); wave w covers full M=64, n-range w*32..w*32+31.
// grid (M/64, N/128).
// ---------------------------------------------------------------------------
__global__ __launch_bounds__(256, 2) void k_gemm(
    const float* __restrict__ A,
    const ushort* __restrict__ Wh, const ushort* __restrict__ Wl,
    const float* __restrict__ bias0, const float* __restrict__ bias1, int nsplit,
    float* __restrict__ C, int N)
{
    __shared__ ushort Ah[64 * 136];
    __shared__ ushort Al[64 * 136];
    const int m0 = blockIdx.x * 64;
    const int n0 = blockIdx.y * 128;
    const int t = threadIdx.x;
    const int wave = t >> 6, lane = t & 63;
    const int quad = lane >> 4, l16 = lane & 15;
    const int wn = wave * 32;

    short8 bh[2][4], bl[2][4];
#pragma unroll
    for (int nt = 0; nt < 2; nt++) {
        const size_t nrow = (size_t)(n0 + wn + nt * 16 + l16) * 128;
#pragma unroll
        for (int kc = 0; kc < 4; kc++) {
            bh[nt][kc] = *(const short8*)(Wh + nrow + kc * 32 + quad * 8);
            bl[nt][kc] = *(const short8*)(Wl + nrow + kc * 32 + quad * 8);
        }
    }

    for (int i = t; i < 64 * 32; i += 256) {
        const int r = i >> 5, c4 = i & 31;
        const float4 f = ((const float4*)(A + (size_t)(m0 + r) * 128))[c4];
        ushort4 h, l;
        h.x = f2bf(f.x); l.x = f2bf(f.x - b2f(h.x));
        h.y = f2bf(f.y); l.y = f2bf(f.y - b2f(h.y));
        h.z = f2bf(f.z); l.z = f2bf(f.z - b2f(h.z));
        h.w = f2bf(f.w); l.w = f2bf(f.w - b2f(h.w));
        *(ushort4*)(&Ah[r * 136 + c4 * 4]) = h;
        *(ushort4*)(&Al[r * 136 + c4 * 4]) = l;
    }
    __syncthreads();

    f32x4 acc[4][2] = {};
#pragma unroll
    for (int kc = 0; kc < 4; kc++) {
        const int kb = kc * 32 + quad * 8;
        short8 ah[4], al[4];
#pragma unroll
        for (int mt = 0; mt < 4; mt++) {
            ah[mt] = *(const short8*)(&Ah[(mt * 16 + l16) * 136 + kb]);
            al[mt] = *(const short8*)(&Al[(mt * 16 + l16) * 136 + kb]);
        }
#pragma unroll
        for (int mt = 0; mt < 4; mt++)
#pragma unroll
            for (int nt = 0; nt < 2; nt++) {
                acc[mt][nt] = __builtin_amdgcn_mfma_f32_16x16x32_bf16(
                                  ah[mt], bh[nt][kc], acc[mt][nt], 0, 0, 0);
                acc[mt][nt] = __builtin_amdgcn_mfma_f32_16x16x32_bf16(
                                  ah[mt], bl[nt][kc], acc[mt][nt], 0, 0, 0);
                acc[mt][nt] = __builtin_amdgcn_mfma_f32_16x16x32_bf16(
                                  al[mt], bh[nt][kc], acc[mt][nt], 0, 0, 0);
            }
    }

#pragma unroll
    for (int nt = 0; nt < 2; nt++) {
        const int n = n0 + wn + nt * 16 + l16;
        const float bv = (n < nsplit) ? bias0[n] : bias1[n - nsplit];
#pragma unroll
        for (int mt = 0; mt < 4; mt++) {
            const int mb = m0 + mt * 16 + quad * 4;
#pragma unroll
            for (int r = 0; r < 4; r++)
                C[(size_t)(mb + r) * N + n] = acc[mt][nt][r] + bv;
        }
    }
}

// ---------------------------------------------------------------------------
// K2: depthwise 3x3 LEPE conv on vcat = [bra v (ch 320+c), win v (128+c-64)]
// writes lepe into out3 (B, L, 128).  grid 65536, block 128
// ---------------------------------------------------------------------------
__global__ __launch_bounds__(128) void k_conv(
                       const float* __restrict__ qkv2,
                       const float* __restrict__ cw, const float* __restrict__ cb,
                       float* __restrict__ out3)
{
    const int pos = blockIdx.x;
    const int c = threadIdx.x;
    const int b = pos >> 14;
    const int hw = pos & 16383;
    const int h = hw >> 7;
    const int w = hw & 127;
    const int ch = (c < 64) ? (320 + c) : (128 + c - 64);
    const float* src = qkv2 + ch;
    float acc = cb[c];
#pragma unroll
    for (int dh = -1; dh <= 1; dh++) {
        const int h2 = h + dh;
        if (h2 < 0 || h2 >= 128) continue;
#pragma unroll
        for (int dw = -1; dw <= 1; dw++) {
            const int w2 = w + dw;
            if (w2 < 0 || w2 >= 128) continue;
            const size_t row = ((size_t)b * 16384 + h2 * 128 + w2) * 384;
            acc = fmaf(src[row], cw[c * 9 + (dh + 1) * 3 + (dw + 1)], acc);
        }
    }
    out3[(size_t)pos * 128 + c] = acc;
}

// ---------------------------------------------------------------------------
// K3: window attention.  grid 8192 = (b,hr,wr,head), block 64 (query pos)
// adds into out3 channels [0,64)
// ---------------------------------------------------------------------------
__global__ __launch_bounds__(64) void k_win(const float* __restrict__ qkv2,
                                            float* __restrict__ out3)
{
    const int bid = blockIdx.x;
    const int n = bid & 7;
    const int win = bid >> 3;
    const int wr = win & 15;
    const int hr = (win >> 4) & 15;
    const int b = win >> 8;
    const int p = threadIdx.x;
    const int wi = p >> 3, wj = p & 7;
    const int h = hr * 8 + wi, w = wr * 8 + wj;
    const size_t row = ((size_t)b * 16384 + h * 128 + w) * 384;

    __shared__ float kk[64][8];
    __shared__ float vv[64][8];
    float q[8];
#pragma unroll
    for (int d = 0; d < 8; d++) {
        q[d] = qkv2[row + n * 8 + d] * SCALE_F;
        kk[p][d] = qkv2[row + 64 + n * 8 + d];
        vv[p][d] = qkv2[row + 128 + n * 8 + d];
    }
    __syncthreads();

    float s[64];
    float m = -1e30f;
#pragma unroll
    for (int j = 0; j < 64; j++) {
        float a = 0.f;
#pragma unroll
        for (int d = 0; d < 8; d++) a = fmaf(q[d], kk[j][d], a);
        s[j] = a;
        m = fmaxf(m, a);
    }
    float sum = 0.f;
#pragma unroll
    for (int j = 0; j < 64; j++) {
        s[j] = expf(s[j] - m);
        sum += s[j];
    }
    const float inv = 1.0f / sum;
    float o[8] = {0.f, 0.f, 0.f, 0.f, 0.f, 0.f, 0.f, 0.f};
#pragma unroll
    for (int j = 0; j < 64; j++) {
        const float pj = s[j] * inv;
#pragma unroll
        for (int d = 0; d < 8; d++) o[d] = fmaf(pj, vv[j][d], o[d]);
    }
    const size_t orow = ((size_t)b * 16384 + h * 128 + w) * 128;
#pragma unroll
    for (int d = 0; d < 8; d++) out3[orow + n * 8 + d] += o[d];
}

// ---------------------------------------------------------------------------
// K4: routing scores input, BIT-IDENTICAL to the passing scalar path:
// per region, bra q/k channel c = bias + fmaf-chain over k=0..63 (in order),
// pooled over positions p=0..63 (in order), * 1/64 at the end.
// grid 1024 = (b, region), block 128 (c<64: q-chan c, c>=64: k-chan c-64)
// ---------------------------------------------------------------------------
__global__ __launch_bounds__(128) void k_scores(const float* __restrict__ x,
                       const float* __restrict__ bw, const float* __restrict__ bb,
                       float* __restrict__ pq, float* __restrict__ pk)
{
    const int r = blockIdx.x;
    const int b = r >> 8;
    const int reg = r & 255;
    const int hr = reg >> 4, wr = reg & 15;
    const int c = threadIdx.x;           // bqkv output column (q: 0..63, k: 64..127)

    float wreg[64];
#pragma unroll
    for (int k = 0; k < 64; k++) wreg[k] = bw[k * 192 + c];
    const float bias = bb[c];

    __shared__ float xs[64][64];         // [pos][bra-channel]
    for (int i = c; i < 64 * 64; i += 128) {
        const int p = i >> 6, ch = i & 63;
        const int h = hr * 8 + (p >> 3), w = wr * 8 + (p & 7);
        xs[p][ch] = x[((size_t)b * 16384 + h * 128 + w) * 128 + 64 + ch];
    }
    __syncthreads();

    float pool = 0.f;
    for (int p = 0; p < 64; p++) {
        float acc = bias;
#pragma unroll
        for (int k = 0; k < 64; k++) acc = fmaf(xs[p][k], wreg[k], acc);
        pool += acc;
    }
    pool *= (1.0f / 64.0f);
    if (c < 64) pq[(size_t)r * 64 + c] = pool;
    else        pk[(size_t)r * 64 + (c - 64)] = pool;
}

// ---------------------------------------------------------------------------
// K5: routing scores + stable top-4.  grid 1024 = (b, i), block 64
// ---------------------------------------------------------------------------
__global__ __launch_bounds__(64) void k_topk(const float* __restrict__ pq,
                       const float* __restrict__ pk, int* __restrict__ idx)
{
    const int bi = blockIdx.x;
    const int b = bi >> 8;
    const int t = threadIdx.x;
    __shared__ float qrow[64];
    __shared__ float s[256];
    qrow[t] = pq[(size_t)bi * 64 + t];
    __syncthreads();
    for (int j4 = 0; j4 < 4; j4++) {
        const int j = j4 * 64 + t;
        const float* krow = pk + ((size_t)b * 256 + j) * 64;
        float a = 0.f;
#pragma unroll
        for (int c = 0; c < 64; c++) a = fmaf(qrow[c], krow[c], a);
        s[j] = a;
    }
    __syncthreads();
    if (t == 0) {
        int chosen[4];
        for (int sel = 0; sel < 4; sel++) {
            float best = -1e30f;
            int bj = -1;
            for (int j = 0; j < 256; j++) {
                bool skip = false;
                for (int u = 0; u < sel; u++) skip = skip || (chosen[u] == j);
                if (!skip && s[j] > best) { best = s[j]; bj = j; }
            }
            chosen[sel] = bj;
            idx[bi * 4 + sel] = bj;
        }
    }
}

// ---------------------------------------------------------------------------
// K6: gathered BRA attention.  grid 8192 = (b, head, region), block 64
// adds into out3 channels [64,128)
// ---------------------------------------------------------------------------
__global__ __launch_bounds__(64) void k_bra(const float* __restrict__ qkv2,
                      const int* __restrict__ idx, float* __restrict__ out3)
{
    const int r = blockIdx.x & 255;
    const int n = (blockIdx.x >> 8) & 7;
    const int b = blockIdx.x >> 11;
    const int p = threadIdx.x;
    const int wi = p >> 3, wj = p & 7;

    __shared__ float kk[256][8];
    __shared__ float vv[256][8];
    __shared__ int regs[4];
    if (p < 4) regs[p] = idx[((b << 8) + r) * 4 + p];
    __syncthreads();

    for (int t = 0; t < 4; t++) {
        const int rt = regs[t];
        const int hr = rt >> 4, wr2 = rt & 15;
        const size_t row = ((size_t)b * 16384 + (hr * 8 + wi) * 128 + (wr2 * 8 + wj)) * 384;
#pragma unroll
        for (int d = 0; d < 8; d++) {
            kk[t * 64 + p][d] = qkv2[row + 256 + n * 8 + d];
            vv[t * 64 + p][d] = qkv2[row + 320 + n * 8 + d];
        }
    }
    const int hq = (r >> 4) * 8 + wi, wq = (r & 15) * 8 + wj;
    const size_t qoff = ((size_t)b * 16384 + hq * 128 + wq) * 384;
    float q[8];
#pragma unroll
    for (int d = 0; d < 8; d++) q[d] = qkv2[qoff + 192 + n * 8 + d] * SCALE_F;
    __syncthreads();

    float m = -1e30f;
    for (int j = 0; j < 256; j++) {
        float a = 0.f;
#pragma unroll
        for (int d = 0; d < 8; d++) a = fmaf(q[d], kk[j][d], a);
        m = fmaxf(m, a);
    }
    float sum = 0.f;
    float o[8] = {0.f, 0.f, 0.f, 0.f, 0.f, 0.f, 0.f, 0.f};
    for (int j = 0; j < 256; j++) {
        float a = 0.f;
#pragma unroll
        for (int d = 0; d < 8; d++) a = fmaf(q[d], kk[j][d], a);
        const float e = expf(a - m);
        sum += e;
#pragma unroll
        for (int d = 0; d < 8; d++) o[d] = fmaf(e, vv[j][d], o[d]);
    }
    const float inv = 1.0f / sum;
    const size_t orow = ((size_t)b * 16384 + hq * 128 + wq) * 128;
#pragma unroll
    for (int d = 0; d < 8; d++) out3[orow + 64 + n * 8 + d] += o[d] * inv;
}

// ---------------------------------------------------------------------------
// K9a: channel-attn partial Gram + partial sq-norms.  grid 512 = (bn, chunk),
// block 256 = (d, e).  Reads position-major cqkv (pos, 384).
// ---------------------------------------------------------------------------
__global__ __launch_bounds__(256) void k_cattn_part(const float* __restrict__ cq,
                                                    float* __restrict__ part)
{
    const int bn = blockIdx.x >> 4;
    const int ch = blockIdx.x & 15;
    const int b = bn >> 3, n = bn & 7;
    const int t = threadIdx.x;
    const int d = t >> 4, e = t & 15;
    __shared__ float qs[128][16];
    __shared__ float ks[128][16];
    const float* base = cq + ((size_t)b * 16384 + ch * 1024) * 384;

    float acc = 0.f, nq = 0.f, nk = 0.f;
    for (int l0 = 0; l0 < 1024; l0 += 128) {
        for (int i = t; i < 128 * 32; i += 256) {
            const int pos = i >> 5;
            const int en = i & 31;
            const int col = (en < 16) ? (n * 16 + en) : (128 + n * 16 + en - 16);
            const float v = base[(size_t)(l0 + pos) * 384 + col];
            if (en < 16) qs[pos][en] = v;
            else         ks[pos][en - 16] = v;
        }
        __syncthreads();
#pragma unroll
        for (int l = 0; l < 128; l++) acc = fmaf(qs[l][d], ks[l][e], acc);
#pragma unroll
        for (int l8 = 0; l8 < 8; l8++) {
            const float qv = qs[l8 * 16 + e][d];
            const float kv = ks[l8 * 16 + d][e];
            nq = fmaf(qv, qv, nq);
            nk = fmaf(kv, kv, nk);
        }
        __syncthreads();
    }
    part[((size_t)bn * 16 + ch) * 288 + t] = acc;

    __shared__ float rq[16][17];
    __shared__ float rk[16][17];
    rq[d][e] = nq;
    rk[e][d] = nk;
    __syncthreads();
    if (t < 16) {
        float sq = 0.f, sk = 0.f;
#pragma unroll
        for (int j = 0; j < 16; j++) { sq += rq[t][j]; sk += rk[t][j]; }
        part[((size_t)bn * 16 + ch) * 288 + 256 + t] = sq;
        part[((size_t)bn * 16 + ch) * 288 + 272 + t] = sk;
    }
}

// ---------------------------------------------------------------------------
// K9b: reduce partials, inv-norms, scale, softmax.  grid 32 = bn, block 256
// ---------------------------------------------------------------------------
__global__ __launch_bounds__(256) void k_cattn_red(const float* __restrict__ part,
                        const float* __restrict__ temp, float* __restrict__ cattn)
{
    const int bn = blockIdx.x;
    const int t = threadIdx.x;
    const int d = t >> 4;
    const int e = t & 15;
    float acc = 0.f;
#pragma unroll
    for (int ch = 0; ch < 16; ch++) acc += part[((size_t)bn * 16 + ch) * 288 + t];
    __shared__ float inorm[32];
    if (t < 32) {
        float s = 0.f;
#pragma unroll
        for (int ch = 0; ch < 16; ch++) s += part[((size_t)bn * 16 + ch) * 288 + 256 + t];
        inorm[t] = 1.0f / fmaxf(sqrtf(s), 1e-12f);
    }
    __syncthreads();
    const int n = bn & 7;
    const float scl = inorm[d] * inorm[16 + e] * temp[n];
    __shared__ float S[16][17];
    S[d][e] = acc * scl;
    __syncthreads();
    if (t < 16) {
        float mm = -1e30f;
#pragma unroll
        for (int e2 = 0; e2 < 16; e2++) mm = fmaxf(mm, S[t][e2]);
        float ex[16];
        float ss = 0.f;
#pragma unroll
        for (int e2 = 0; e2 < 16; e2++) {
            ex[e2] = expf(S[t][e2] - mm);
            ss += ex[e2];
        }
        const float inv = 1.0f / ss;
#pragma unroll
        for (int e2 = 0; e2 < 16; e2++) cattn[(bn * 16 + t) * 16 + e2] = ex[e2] * inv;
    }
}

// ---------------------------------------------------------------------------
// K10: cout = cattn @ cv (position-major cv), written (B, L, 128) into out3
// grid 8192 = (bn, l/64), block 64
// ---------------------------------------------------------------------------
__global__ __launch_bounds__(64) void k_cout(const float* __restrict__ cattn,
                       const float* __restrict__ cq, float* __restrict__ out3)
{
    const int blk = blockIdx.x;
    const int bn = blk >> 8;
    const int b = bn >> 3, n = bn & 7;
    const int l0 = (blk & 255) * 64;
    const int t = threadIdx.x;
    __shared__ float A[16][17];
    for (int i = t; i < 256; i += 64) A[i >> 4][i & 15] = cattn[bn * 256 + i];
    __syncthreads();
    const int pos = l0 + t;
    const float* vp = cq + ((size_t)b * 16384 + pos) * 384 + 256 + n * 16;
    float v[16];
#pragma unroll
    for (int e4 = 0; e4 < 4; e4++) {
        const float4 f = ((const float4*)vp)[e4];
        v[e4 * 4 + 0] = f.x; v[e4 * 4 + 1] = f.y; v[e4 * 4 + 2] = f.z; v[e4 * 4 + 3] = f.w;
    }
    float acc[16];
#pragma unroll
    for (int d = 0; d < 16; d++) acc[d] = 0.f;
#pragma unroll
    for (int e = 0; e < 16; e++) {
#pragma unroll
        for (int d = 0; d < 16; d++) acc[d] = fmaf(A[d][e], v[e], acc[d]);
    }
    float* op = out3 + ((size_t)b * 16384 + pos) * 128 + n * 16;
#pragma unroll
    for (int d4 = 0; d4 < 4; d4++) {
        float4 f;
        f.x = acc[d4 * 4 + 0]; f.y = acc[d4 * 4 + 1]; f.z = acc[d4 * 4 + 2]; f.w = acc[d4 * 4 + 3];
        ((float4*)op)[d4] = f;
    }
}

// ---------------------------------------------------------------------------
extern "C" void kernel_launch(void* const* d_in, const int* in_sizes, int n_in,
                              void* d_out, int out_size, void* d_ws, size_t ws_size,
                              hipStream_t stream)
{
    const float* x       = (const float*)d_in[0];
    const float* wqkv_w  = (const float*)d_in[1];
    const float* wqkv_b  = (const float*)d_in[2];
    const float* bqkv_w  = (const float*)d_in[3];
    const float* bqkv_b  = (const float*)d_in[4];
    const float* lepe_w  = (const float*)d_in[5];
    const float* lepe_b  = (const float*)d_in[6];
    const float* ca_qkv_w = (const float*)d_in[7];
    const float* ca_qkv_b = (const float*)d_in[8];
    const float* ca_temp  = (const float*)d_in[9];
    const float* ca_proj_w = (const float*)d_in[10];
    const float* ca_proj_b = (const float*)d_in[11];

    float* ws = (float*)d_ws;
    float* qkv2 = ws;                         // 65536*384 floats (pos-major)
    float* cqkv = ws;                         // alias (qkv2 dead after k_bra)
    float* out3 = ws + 25165824;              // 65536*128 floats
    float* aux  = out3 + 8388608;             // aux region
    float* pq   = aux;                        // 65536 (dead after k_topk)
    float* pk   = pq + 65536;                 // 65536 (dead after k_topk)
    int*   idx  = (int*)(pk + 65536);         // 4096 ints (dead after k_bra)
    float* part = aux;                        // alias pq..idx: 147456
    float* catn = aux + 147456;               // 8192
    // wt1 aliases aux (read by gemm1 BEFORE k_scores writes pq); wt2/wt3 in tail
    ushort* wt1h = (ushort*)aux;              // 49152 ushorts = 24576 floats
    ushort* wt1l = (ushort*)(aux + 24576);    // 24576 floats
    float* tail = aux + 155648;
    ushort* wt2h = (ushort*)tail;             // 24576 floats
    ushort* wt2l = (ushort*)(tail + 24576);   // 24576 floats
    ushort* wt3h = (ushort*)(tail + 49152);   // 8192 floats
    ushort* wt3l = (ushort*)(tail + 57344);   // 8192 floats

    k_pack<<<896, 128, 0, stream>>>(wqkv_w, bqkv_w, ca_qkv_w, ca_proj_w,
                                    wt1h, wt1l, wt2h, wt2l, wt3h, wt3l);
    k_gemm<<<dim3(1024, 3), 256, 0, stream>>>(x, wt1h, wt1l,
                                              wqkv_b, bqkv_b, 192, qkv2, 384);
    k_conv<<<65536, 128, 0, stream>>>(qkv2, lepe_w, lepe_b, out3);
    k_win<<<8192, 64, 0, stream>>>(qkv2, out3);
    k_scores<<<1024, 128, 0, stream>>>(x, bqkv_w, bqkv_b, pq, pk);
    k_topk<<<1024, 64, 0, stream>>>(pq, pk, idx);
    k_bra<<<8192, 64, 0, stream>>>(qkv2, idx, out3);
    k_gemm<<<dim3(1024, 3), 256, 0, stream>>>(out3, wt2h, wt2l,
                                              ca_qkv_b, ca_qkv_b, 384, cqkv, 384);
    k_cattn_part<<<512, 256, 0, stream>>>(cqkv, part);
    k_cattn_red<<<32, 256, 0, stream>>>(part, ca_temp, catn);
    k_cout<<<8192, 64, 0, stream>>>(catn, cqkv, out3);
    k_gemm<<<dim3(1024, 1), 256, 0, stream>>>(out3, wt3h, wt3l,
                                              ca_proj_b, ca_proj_b, 128,
                                              (float*)d_out, 128);
}

// Round 9
// 596.082 us; speedup vs baseline: 6.1427x; 1.1673x over previous
//
#include <hip/hip_runtime.h>
#include <math.h>

#define SCALE_F 0.08838834764831843f

typedef __attribute__((ext_vector_type(8))) short short8;
typedef __attribute__((ext_vector_type(4))) float f32x4;

__device__ __forceinline__ ushort f2bf(float f) {
    unsigned u = __float_as_uint(f);
    u = (u + 0x7fff + ((u >> 16) & 1)) >> 16;   // RNE
    return (ushort)u;
}
__device__ __forceinline__ float b2f(ushort h) {
    return __uint_as_float(((unsigned)h) << 16);
}

// ---------------------------------------------------------------------------
// K0: pack weights to bf16 hi/lo pairs, transposed to (N,128) k-contiguous.
// wt1 (384x128): block-diag [ww | 0 ; 0 | bw].  wt2 (384x128) = ca_qkv_w^T.
// wt3 (128x128) = ca_proj_w^T.  grid 896, block 128.
// ---------------------------------------------------------------------------
__global__ __launch_bounds__(128) void k_pack(
    const float* __restrict__ ww, const float* __restrict__ bw,
    const float* __restrict__ qw, const float* __restrict__ pw,
    ushort* __restrict__ wt1h, ushort* __restrict__ wt1l,
    ushort* __restrict__ wt2h, ushort* __restrict__ wt2l,
    ushort* __restrict__ wt3h, ushort* __restrict__ wt3l)
{
    const int blk = blockIdx.x;
    const int t = threadIdx.x;
    float v;
    ushort *dh, *dl;
    int off;
    if (blk < 384) {
        const int n = blk;
        if (n < 192) v = (t < 64) ? ww[t * 192 + n] : 0.f;
        else         v = (t >= 64) ? bw[(t - 64) * 192 + (n - 192)] : 0.f;
        dh = wt1h; dl = wt1l; off = n * 128 + t;
    } else if (blk < 768) {
        const int n = blk - 384;
        v = qw[t * 384 + n];
        dh = wt2h; dl = wt2l; off = n * 128 + t;
    } else {
        const int n = blk - 768;
        v = pw[t * 128 + n];
        dh = wt3h; dl = wt3l; off = n * 128 + t;
    }
    const ushort h = f2bf(v);
    dh[off] = h;
    dl[off] = f2bf(v - b2f(h));
}

// ---------------------------------------------------------------------------
// K-GEMM (split precision): C = A(M x 128 fp32) @ W^T + bias computed as
// ah*bh + ah*bl + al*bh in bf16 MFMA (fp32-accurate to ~4e-6 rel).
// A-tile M=64 staged hi/lo in LDS; B hi/lo frags from global (L2-hot).
// block 256 (4 waves); wave w covers full M=64, n-range w*32..w*32+31.
// grid (M/64, N/128).
// ---------------------------------------------------------------------------
__global__ __launch_bounds__(256, 2) void k_gemm(
    const float* __restrict__ A,
    const ushort* __restrict__ Wh, const ushort* __restrict__ Wl,
    const float* __restrict__ bias0, const float* __restrict__ bias1, int nsplit,
    float* __restrict__ C, int N)
{
    __shared__ ushort Ah[64 * 136];
    __shared__ ushort Al[64 * 136];
    const int m0 = blockIdx.x * 64;
    const int n0 = blockIdx.y * 128;
    const int t = threadIdx.x;
    const int wave = t >> 6, lane = t & 63;
    const int quad = lane >> 4, l16 = lane & 15;
    const int wn = wave * 32;

    short8 bh[2][4], bl[2][4];
#pragma unroll
    for (int nt = 0; nt < 2; nt++) {
        const size_t nrow = (size_t)(n0 + wn + nt * 16 + l16) * 128;
#pragma unroll
        for (int kc = 0; kc < 4; kc++) {
            bh[nt][kc] = *(const short8*)(Wh + nrow + kc * 32 + quad * 8);
            bl[nt][kc] = *(const short8*)(Wl + nrow + kc * 32 + quad * 8);
        }
    }

    for (int i = t; i < 64 * 32; i += 256) {
        const int r = i >> 5, c4 = i & 31;
        const float4 f = ((const float4*)(A + (size_t)(m0 + r) * 128))[c4];
        ushort4 h, l;
        h.x = f2bf(f.x); l.x = f2bf(f.x - b2f(h.x));
        h.y = f2bf(f.y); l.y = f2bf(f.y - b2f(h.y));
        h.z = f2bf(f.z); l.z = f2bf(f.z - b2f(h.z));
        h.w = f2bf(f.w); l.w = f2bf(f.w - b2f(h.w));
        *(ushort4*)(&Ah[r * 136 + c4 * 4]) = h;
        *(ushort4*)(&Al[r * 136 + c4 * 4]) = l;
    }
    __syncthreads();

    f32x4 acc[4][2] = {};
#pragma unroll
    for (int kc = 0; kc < 4; kc++) {
        const int kb = kc * 32 + quad * 8;
        short8 ah[4], al[4];
#pragma unroll
        for (int mt = 0; mt < 4; mt++) {
            ah[mt] = *(const short8*)(&Ah[(mt * 16 + l16) * 136 + kb]);
            al[mt] = *(const short8*)(&Al[(mt * 16 + l16) * 136 + kb]);
        }
#pragma unroll
        for (int mt = 0; mt < 4; mt++)
#pragma unroll
            for (int nt = 0; nt < 2; nt++) {
                acc[mt][nt] = __builtin_amdgcn_mfma_f32_16x16x32_bf16(
                                  ah[mt], bh[nt][kc], acc[mt][nt], 0, 0, 0);
                acc[mt][nt] = __builtin_amdgcn_mfma_f32_16x16x32_bf16(
                                  ah[mt], bl[nt][kc], acc[mt][nt], 0, 0, 0);
                acc[mt][nt] = __builtin_amdgcn_mfma_f32_16x16x32_bf16(
                                  al[mt], bh[nt][kc], acc[mt][nt], 0, 0, 0);
            }
    }

#pragma unroll
    for (int nt = 0; nt < 2; nt++) {
        const int n = n0 + wn + nt * 16 + l16;
        const float bv = (n < nsplit) ? bias0[n] : bias1[n - nsplit];
#pragma unroll
        for (int mt = 0; mt < 4; mt++) {
            const int mb = m0 + mt * 16 + quad * 4;
#pragma unroll
            for (int r = 0; r < 4; r++)
                C[(size_t)(mb + r) * N + n] = acc[mt][nt][r] + bv;
        }
    }
}

// ---------------------------------------------------------------------------
// K2: depthwise 3x3 LEPE conv on vcat = [bra v (ch 320+c), win v (128+c-64)]
// writes lepe into out3 (B, L, 128).  grid 65536, block 128
// ---------------------------------------------------------------------------
__global__ __launch_bounds__(128) void k_conv(
                       const float* __restrict__ qkv2,
                       const float* __restrict__ cw, const float* __restrict__ cb,
                       float* __restrict__ out3)
{
    const int pos = blockIdx.x;
    const int c = threadIdx.x;
    const int b = pos >> 14;
    const int hw = pos & 16383;
    const int h = hw >> 7;
    const int w = hw & 127;
    const int ch = (c < 64) ? (320 + c) : (128 + c - 64);
    const float* src = qkv2 + ch;
    float acc = cb[c];
#pragma unroll
    for (int dh = -1; dh <= 1; dh++) {
        const int h2 = h + dh;
        if (h2 < 0 || h2 >= 128) continue;
#pragma unroll
        for (int dw = -1; dw <= 1; dw++) {
            const int w2 = w + dw;
            if (w2 < 0 || w2 >= 128) continue;
            const size_t row = ((size_t)b * 16384 + h2 * 128 + w2) * 384;
            acc = fmaf(src[row], cw[c * 9 + (dh + 1) * 3 + (dw + 1)], acc);
        }
    }
    out3[(size_t)pos * 128 + c] = acc;
}

// ---------------------------------------------------------------------------
// K3: window attention.  grid 8192 = (b,hr,wr,head), block 64 (query pos)
// adds into out3 channels [0,64)
// ---------------------------------------------------------------------------
__global__ __launch_bounds__(64) void k_win(const float* __restrict__ qkv2,
                                            float* __restrict__ out3)
{
    const int bid = blockIdx.x;
    const int n = bid & 7;
    const int win = bid >> 3;
    const int wr = win & 15;
    const int hr = (win >> 4) & 15;
    const int b = win >> 8;
    const int p = threadIdx.x;
    const int wi = p >> 3, wj = p & 7;
    const int h = hr * 8 + wi, w = wr * 8 + wj;
    const size_t row = ((size_t)b * 16384 + h * 128 + w) * 384;

    __shared__ float kk[64][8];
    __shared__ float vv[64][8];
    float q[8];
#pragma unroll
    for (int d = 0; d < 8; d++) {
        q[d] = qkv2[row + n * 8 + d] * SCALE_F;
        kk[p][d] = qkv2[row + 64 + n * 8 + d];
        vv[p][d] = qkv2[row + 128 + n * 8 + d];
    }
    __syncthreads();

    float s[64];
    float m = -1e30f;
#pragma unroll
    for (int j = 0; j < 64; j++) {
        float a = 0.f;
#pragma unroll
        for (int d = 0; d < 8; d++) a = fmaf(q[d], kk[j][d], a);
        s[j] = a;
        m = fmaxf(m, a);
    }
    float sum = 0.f;
#pragma unroll
    for (int j = 0; j < 64; j++) {
        s[j] = expf(s[j] - m);
        sum += s[j];
    }
    const float inv = 1.0f / sum;
    float o[8] = {0.f, 0.f, 0.f, 0.f, 0.f, 0.f, 0.f, 0.f};
#pragma unroll
    for (int j = 0; j < 64; j++) {
        const float pj = s[j] * inv;
#pragma unroll
        for (int d = 0; d < 8; d++) o[d] = fmaf(pj, vv[j][d], o[d]);
    }
    const size_t orow = ((size_t)b * 16384 + h * 128 + w) * 128;
#pragma unroll
    for (int d = 0; d < 8; d++) out3[orow + n * 8 + d] += o[d];
}

// ---------------------------------------------------------------------------
// K4: routing scores input, BIT-IDENTICAL to the passing scalar path:
// per region, bra q/k channel c = bias + fmaf-chain over k=0..63 (in order),
// pooled over positions p=0..63 (in order), * 1/64 at the end.
// grid 1024 = (b, region), block 128 (c<64: q-chan c, c>=64: k-chan c-64)
// ---------------------------------------------------------------------------
__global__ __launch_bounds__(128) void k_scores(const float* __restrict__ x,
                       const float* __restrict__ bw, const float* __restrict__ bb,
                       float* __restrict__ pq, float* __restrict__ pk)
{
    const int r = blockIdx.x;
    const int b = r >> 8;
    const int reg = r & 255;
    const int hr = reg >> 4, wr = reg & 15;
    const int c = threadIdx.x;           // bqkv output column (q: 0..63, k: 64..127)

    float wreg[64];
#pragma unroll
    for (int k = 0; k < 64; k++) wreg[k] = bw[k * 192 + c];
    const float bias = bb[c];

    __shared__ float xs[64][64];         // [pos][bra-channel]
    for (int i = c; i < 64 * 64; i += 128) {
        const int p = i >> 6, ch = i & 63;
        const int h = hr * 8 + (p >> 3), w = wr * 8 + (p & 7);
        xs[p][ch] = x[((size_t)b * 16384 + h * 128 + w) * 128 + 64 + ch];
    }
    __syncthreads();

    float pool = 0.f;
    for (int p = 0; p < 64; p++) {
        float acc = bias;
#pragma unroll
        for (int k = 0; k < 64; k++) acc = fmaf(xs[p][k], wreg[k], acc);
        pool += acc;
    }
    pool *= (1.0f / 64.0f);
    if (c < 64) pq[(size_t)r * 64 + c] = pool;
    else        pk[(size_t)r * 64 + (c - 64)] = pool;
}

// ---------------------------------------------------------------------------
// K5: routing scores + stable top-4.  grid 1024 = (b, i), block 64
// ---------------------------------------------------------------------------
__global__ __launch_bounds__(64) void k_topk(const float* __restrict__ pq,
                       const float* __restrict__ pk, int* __restrict__ idx)
{
    const int bi = blockIdx.x;
    const int b = bi >> 8;
    const int t = threadIdx.x;
    __shared__ float qrow[64];
    __shared__ float s[256];
    qrow[t] = pq[(size_t)bi * 64 + t];
    __syncthreads();
    for (int j4 = 0; j4 < 4; j4++) {
        const int j = j4 * 64 + t;
        const float* krow = pk + ((size_t)b * 256 + j) * 64;
        float a = 0.f;
#pragma unroll
        for (int c = 0; c < 64; c++) a = fmaf(qrow[c], krow[c], a);
        s[j] = a;
    }
    __syncthreads();
    if (t == 0) {
        int chosen[4];
        for (int sel = 0; sel < 4; sel++) {
            float best = -1e30f;
            int bj = -1;
            for (int j = 0; j < 256; j++) {
                bool skip = false;
                for (int u = 0; u < sel; u++) skip = skip || (chosen[u] == j);
                if (!skip && s[j] > best) { best = s[j]; bj = j; }
            }
            chosen[sel] = bj;
            idx[bi * 4 + sel] = bj;
        }
    }
}

// ---------------------------------------------------------------------------
// K6: gathered BRA attention, 2 waves per block.  grid 8192 = (b, head, region),
// block 128: wave h handles keys [h*128, h*128+128) with chunked online
// softmax (32 scores register-cached -> dots computed once); halves merged
// via LDS (reusing kk).  Adds into out3 channels [64,128).
// ---------------------------------------------------------------------------
__global__ __launch_bounds__(128) void k_bra(const float* __restrict__ qkv2,
                      const int* __restrict__ idx, float* __restrict__ out3)
{
    const int r = blockIdx.x & 255;
    const int n = (blockIdx.x >> 8) & 7;
    const int b = blockIdx.x >> 11;
    const int tid = threadIdx.x;
    const int q = tid & 63;
    const int half = tid >> 6;

    __shared__ float kk[256][8];
    __shared__ float vv[256][8];

    // stage K/V of the 4 gathered regions (head's 8 channels), float4 x2 each
    for (int i = tid; i < 512; i += 128) {
        const int isv = (i >= 256);
        const int row = i & 255;
        const int rt = idx[((b << 8) + r) * 4 + (row >> 6)];
        const int p = row & 63;
        const int hh = (rt >> 4) * 8 + (p >> 3);
        const int ww = (rt & 15) * 8 + (p & 7);
        const float* src = qkv2 + ((size_t)b * 16384 + hh * 128 + ww) * 384
                           + (isv ? 320 : 256) + n * 8;
        const float4 f0 = ((const float4*)src)[0];
        const float4 f1 = ((const float4*)src)[1];
        float* dst = isv ? &vv[row][0] : &kk[row][0];
        ((float4*)dst)[0] = f0;
        ((float4*)dst)[1] = f1;
    }

    const int hq = (r >> 4) * 8 + (q >> 3), wq = (r & 15) * 8 + (q & 7);
    const size_t qoff = ((size_t)b * 16384 + hq * 128 + wq) * 384 + 192 + n * 8;
    float qv[8];
    {
        const float4 f0 = ((const float4*)(qkv2 + qoff))[0];
        const float4 f1 = ((const float4*)(qkv2 + qoff))[1];
        qv[0] = f0.x * SCALE_F; qv[1] = f0.y * SCALE_F;
        qv[2] = f0.z * SCALE_F; qv[3] = f0.w * SCALE_F;
        qv[4] = f1.x * SCALE_F; qv[5] = f1.y * SCALE_F;
        qv[6] = f1.z * SCALE_F; qv[7] = f1.w * SCALE_F;
    }
    __syncthreads();

    float m = -1e30f, sum = 0.f;
    float o[8] = {0.f, 0.f, 0.f, 0.f, 0.f, 0.f, 0.f, 0.f};
    const int j0 = half * 128;
    for (int c = 0; c < 4; c++) {
        float s[32];
        float mc = -1e30f;
        const int jb = j0 + c * 32;
#pragma unroll
        for (int j = 0; j < 32; j++) {
            float a = 0.f;
#pragma unroll
            for (int d = 0; d < 8; d++) a = fmaf(qv[d], kk[jb + j][d], a);
            s[j] = a;
            mc = fmaxf(mc, a);
        }
        const float m_new = fmaxf(m, mc);
        const float corr = expf(m - m_new);
        sum *= corr;
#pragma unroll
        for (int d = 0; d < 8; d++) o[d] *= corr;
#pragma unroll
        for (int j = 0; j < 32; j++) {
            const float e = expf(s[j] - m_new);
            sum += e;
#pragma unroll
            for (int d = 0; d < 8; d++) o[d] = fmaf(e, vv[jb + j][d], o[d]);
        }
        m = m_new;
    }

    // merge the two halves (reuse kk as scratch: 64 q x 12 floats = 3 KB)
    __syncthreads();
    float* st = &kk[0][0];
    if (half == 1) {
        float* p = st + q * 12;
        p[0] = m; p[1] = sum;
#pragma unroll
        for (int d = 0; d < 8; d++) p[2 + d] = o[d];
    }
    __syncthreads();
    if (half == 0) {
        const float* p = st + q * 12;
        const float m1 = p[0], s1 = p[1];
        const float mN = fmaxf(m, m1);
        const float c0 = expf(m - mN), c1 = expf(m1 - mN);
        const float inv = 1.0f / (sum * c0 + s1 * c1);
        const size_t orow = ((size_t)b * 16384 + hq * 128 + wq) * 128;
#pragma unroll
        for (int d = 0; d < 8; d++)
            out3[orow + 64 + n * 8 + d] += (o[d] * c0 + p[2 + d] * c1) * inv;
    }
}

// ---------------------------------------------------------------------------
// K9a: channel-attn partial Gram + partial sq-norms.  grid 512 = (bn, chunk),
// block 256 = (d, e).  Reads position-major cqkv (pos, 384).
// ---------------------------------------------------------------------------
__global__ __launch_bounds__(256) void k_cattn_part(const float* __restrict__ cq,
                                                    float* __restrict__ part)
{
    const int bn = blockIdx.x >> 4;
    const int ch = blockIdx.x & 15;
    const int b = bn >> 3, n = bn & 7;
    const int t = threadIdx.x;
    const int d = t >> 4, e = t & 15;
    __shared__ float qs[128][16];
    __shared__ float ks[128][16];
    const float* base = cq + ((size_t)b * 16384 + ch * 1024) * 384;

    float acc = 0.f, nq = 0.f, nk = 0.f;
    for (int l0 = 0; l0 < 1024; l0 += 128) {
        for (int i = t; i < 128 * 32; i += 256) {
            const int pos = i >> 5;
            const int en = i & 31;
            const int col = (en < 16) ? (n * 16 + en) : (128 + n * 16 + en - 16);
            const float v = base[(size_t)(l0 + pos) * 384 + col];
            if (en < 16) qs[pos][en] = v;
            else         ks[pos][en - 16] = v;
        }
        __syncthreads();
#pragma unroll
        for (int l = 0; l < 128; l++) acc = fmaf(qs[l][d], ks[l][e], acc);
#pragma unroll
        for (int l8 = 0; l8 < 8; l8++) {
            const float qv = qs[l8 * 16 + e][d];
            const float kv = ks[l8 * 16 + d][e];
            nq = fmaf(qv, qv, nq);
            nk = fmaf(kv, kv, nk);
        }
        __syncthreads();
    }
    part[((size_t)bn * 16 + ch) * 288 + t] = acc;

    __shared__ float rq[16][17];
    __shared__ float rk[16][17];
    rq[d][e] = nq;
    rk[e][d] = nk;
    __syncthreads();
    if (t < 16) {
        float sq = 0.f, sk = 0.f;
#pragma unroll
        for (int j = 0; j < 16; j++) { sq += rq[t][j]; sk += rk[t][j]; }
        part[((size_t)bn * 16 + ch) * 288 + 256 + t] = sq;
        part[((size_t)bn * 16 + ch) * 288 + 272 + t] = sk;
    }
}

// ---------------------------------------------------------------------------
// K9b: reduce partials, inv-norms, scale, softmax.  grid 32 = bn, block 256
// ---------------------------------------------------------------------------
__global__ __launch_bounds__(256) void k_cattn_red(const float* __restrict__ part,
                        const float* __restrict__ temp, float* __restrict__ cattn)
{
    const int bn = blockIdx.x;
    const int t = threadIdx.x;
    const int d = t >> 4;
    const int e = t & 15;
    float acc = 0.f;
#pragma unroll
    for (int ch = 0; ch < 16; ch++) acc += part[((size_t)bn * 16 + ch) * 288 + t];
    __shared__ float inorm[32];
    if (t < 32) {
        float s = 0.f;
#pragma unroll
        for (int ch = 0; ch < 16; ch++) s += part[((size_t)bn * 16 + ch) * 288 + 256 + t];
        inorm[t] = 1.0f / fmaxf(sqrtf(s), 1e-12f);
    }
    __syncthreads();
    const int n = bn & 7;
    const float scl = inorm[d] * inorm[16 + e] * temp[n];
    __shared__ float S[16][17];
    S[d][e] = acc * scl;
    __syncthreads();
    if (t < 16) {
        float mm = -1e30f;
#pragma unroll
        for (int e2 = 0; e2 < 16; e2++) mm = fmaxf(mm, S[t][e2]);
        float ex[16];
        float ss = 0.f;
#pragma unroll
        for (int e2 = 0; e2 < 16; e2++) {
            ex[e2] = expf(S[t][e2] - mm);
            ss += ex[e2];
        }
        const float inv = 1.0f / ss;
#pragma unroll
        for (int e2 = 0; e2 < 16; e2++) cattn[(bn * 16 + t) * 16 + e2] = ex[e2] * inv;
    }
}

// ---------------------------------------------------------------------------
// K10: cout = cattn @ cv (position-major cv), written (B, L, 128) into out3
// grid 8192 = (bn, l/64), block 64
// ---------------------------------------------------------------------------
__global__ __launch_bounds__(64) void k_cout(const float* __restrict__ cattn,
                       const float* __restrict__ cq, float* __restrict__ out3)
{
    const int blk = blockIdx.x;
    const int bn = blk >> 8;
    const int b = bn >> 3, n = bn & 7;
    const int l0 = (blk & 255) * 64;
    const int t = threadIdx.x;
    __shared__ float A[16][17];
    for (int i = t; i < 256; i += 64) A[i >> 4][i & 15] = cattn[bn * 256 + i];
    __syncthreads();
    const int pos = l0 + t;
    const float* vp = cq + ((size_t)b * 16384 + pos) * 384 + 256 + n * 16;
    float v[16];
#pragma unroll
    for (int e4 = 0; e4 < 4; e4++) {
        const float4 f = ((const float4*)vp)[e4];
        v[e4 * 4 + 0] = f.x; v[e4 * 4 + 1] = f.y; v[e4 * 4 + 2] = f.z; v[e4 * 4 + 3] = f.w;
    }
    float acc[16];
#pragma unroll
    for (int d = 0; d < 16; d++) acc[d] = 0.f;
#pragma unroll
    for (int e = 0; e < 16; e++) {
#pragma unroll
        for (int d = 0; d < 16; d++) acc[d] = fmaf(A[d][e], v[e], acc[d]);
    }
    float* op = out3 + ((size_t)b * 16384 + pos) * 128 + n * 16;
#pragma unroll
    for (int d4 = 0; d4 < 4; d4++) {
        float4 f;
        f.x = acc[d4 * 4 + 0]; f.y = acc[d4 * 4 + 1]; f.z = acc[d4 * 4 + 2]; f.w = acc[d4 * 4 + 3];
        ((float4*)op)[d4] = f;
    }
}

// ---------------------------------------------------------------------------
extern "C" void kernel_launch(void* const* d_in, const int* in_sizes, int n_in,
                              void* d_out, int out_size, void* d_ws, size_t ws_size,
                              hipStream_t stream)
{
    const float* x       = (const float*)d_in[0];
    const float* wqkv_w  = (const float*)d_in[1];
    const float* wqkv_b  = (const float*)d_in[2];
    const float* bqkv_w  = (const float*)d_in[3];
    const float* bqkv_b  = (const float*)d_in[4];
    const float* lepe_w  = (const float*)d_in[5];
    const float* lepe_b  = (const float*)d_in[6];
    const float* ca_qkv_w = (const float*)d_in[7];
    const float* ca_qkv_b = (const float*)d_in[8];
    const float* ca_temp  = (const float*)d_in[9];
    const float* ca_proj_w = (const float*)d_in[10];
    const float* ca_proj_b = (const float*)d_in[11];

    float* ws = (float*)d_ws;
    float* qkv2 = ws;                         // 65536*384 floats (pos-major)
    float* cqkv = ws;                         // alias (qkv2 dead after k_bra)
    float* out3 = ws + 25165824;              // 65536*128 floats
    float* aux  = out3 + 8388608;             // aux region
    float* pq   = aux;                        // 65536 (dead after k_topk)
    float* pk   = pq + 65536;                 // 65536 (dead after k_topk)
    int*   idx  = (int*)(pk + 65536);         // 4096 ints (dead after k_bra)
    float* part = aux;                        // alias pq..idx: 147456
    float* catn = aux + 147456;               // 8192
    // wt1 aliases aux (read by gemm1 BEFORE k_scores writes pq); wt2/wt3 in tail
    ushort* wt1h = (ushort*)aux;              // 49152 ushorts = 24576 floats
    ushort* wt1l = (ushort*)(aux + 24576);    // 24576 floats
    float* tail = aux + 155648;
    ushort* wt2h = (ushort*)tail;             // 24576 floats
    ushort* wt2l = (ushort*)(tail + 24576);   // 24576 floats
    ushort* wt3h = (ushort*)(tail + 49152);   // 8192 floats
    ushort* wt3l = (ushort*)(tail + 57344);   // 8192 floats

    k_pack<<<896, 128, 0, stream>>>(wqkv_w, bqkv_w, ca_qkv_w, ca_proj_w,
                                    wt1h, wt1l, wt2h, wt2l, wt3h, wt3l);
    k_gemm<<<dim3(1024, 3), 256, 0, stream>>>(x, wt1h, wt1l,
                                              wqkv_b, bqkv_b, 192, qkv2, 384);
    k_conv<<<65536, 128, 0, stream>>>(qkv2, lepe_w, lepe_b, out3);
    k_win<<<8192, 64, 0, stream>>>(qkv2, out3);
    k_scores<<<1024, 128, 0, stream>>>(x, bqkv_w, bqkv_b, pq, pk);
    k_topk<<<1024, 64, 0, stream>>>(pq, pk, idx);
    k_bra<<<8192, 128, 0, stream>>>(qkv2, idx, out3);
    k_gemm<<<dim3(1024, 3), 256, 0, stream>>>(out3, wt2h, wt2l,
                                              ca_qkv_b, ca_qkv_b, 384, cqkv, 384);
    k_cattn_part<<<512, 256, 0, stream>>>(cqkv, part);
    k_cattn_red<<<32, 256, 0, stream>>>(part, ca_temp, catn);
    k_cout<<<8192, 64, 0, stream>>>(catn, cqkv, out3);
    k_gemm<<<dim3(1024, 1), 256, 0, stream>>>(out3, wt3h, wt3l,
                                              ca_proj_b, ca_proj_b, 128,
                                              (float*)d_out, 128);
}

// Round 10
// 537.718 us; speedup vs baseline: 6.8095x; 1.1085x over previous
//
#include <hip/hip_runtime.h>
#include <math.h>

#define SCALE_F 0.08838834764831843f

typedef __attribute__((ext_vector_type(8))) short short8;
typedef __attribute__((ext_vector_type(4))) float f32x4;

__device__ __forceinline__ ushort f2bf(float f) {
    unsigned u = __float_as_uint(f);
    u = (u + 0x7fff + ((u >> 16) & 1)) >> 16;   // RNE
    return (ushort)u;
}
__device__ __forceinline__ float b2f(ushort h) {
    return __uint_as_float(((unsigned)h) << 16);
}

// ---------------------------------------------------------------------------
// K0: pack weights to bf16 hi/lo pairs, transposed to (N,128) k-contiguous.
// wt1 (384x128): block-diag [ww | 0 ; 0 | bw].  wt2 (384x128) = ca_qkv_w^T.
// wt3 (128x128) = ca_proj_w^T.  grid 896, block 128.
// ---------------------------------------------------------------------------
__global__ __launch_bounds__(128) void k_pack(
    const float* __restrict__ ww, const float* __restrict__ bw,
    const float* __restrict__ qw, const float* __restrict__ pw,
    ushort* __restrict__ wt1h, ushort* __restrict__ wt1l,
    ushort* __restrict__ wt2h, ushort* __restrict__ wt2l,
    ushort* __restrict__ wt3h, ushort* __restrict__ wt3l)
{
    const int blk = blockIdx.x;
    const int t = threadIdx.x;
    float v;
    ushort *dh, *dl;
    int off;
    if (blk < 384) {
        const int n = blk;
        if (n < 192) v = (t < 64) ? ww[t * 192 + n] : 0.f;
        else         v = (t >= 64) ? bw[(t - 64) * 192 + (n - 192)] : 0.f;
        dh = wt1h; dl = wt1l; off = n * 128 + t;
    } else if (blk < 768) {
        const int n = blk - 384;
        v = qw[t * 384 + n];
        dh = wt2h; dl = wt2l; off = n * 128 + t;
    } else {
        const int n = blk - 768;
        v = pw[t * 128 + n];
        dh = wt3h; dl = wt3l; off = n * 128 + t;
    }
    const ushort h = f2bf(v);
    dh[off] = h;
    dl[off] = f2bf(v - b2f(h));
}

// ---------------------------------------------------------------------------
// K-GEMM (split precision): C = A(M x 128 fp32) @ W^T + bias computed as
// ah*bh + ah*bl + al*bh in bf16 MFMA (fp32-accurate to ~4e-6 rel).
// ---------------------------------------------------------------------------
__global__ __launch_bounds__(256, 2) void k_gemm(
    const float* __restrict__ A,
    const ushort* __restrict__ Wh, const ushort* __restrict__ Wl,
    const float* __restrict__ bias0, const float* __restrict__ bias1, int nsplit,
    float* __restrict__ C, int N)
{
    __shared__ ushort Ah[64 * 136];
    __shared__ ushort Al[64 * 136];
    const int m0 = blockIdx.x * 64;
    const int n0 = blockIdx.y * 128;
    const int t = threadIdx.x;
    const int wave = t >> 6, lane = t & 63;
    const int quad = lane >> 4, l16 = lane & 15;
    const int wn = wave * 32;

    short8 bh[2][4], bl[2][4];
#pragma unroll
    for (int nt = 0; nt < 2; nt++) {
        const size_t nrow = (size_t)(n0 + wn + nt * 16 + l16) * 128;
#pragma unroll
        for (int kc = 0; kc < 4; kc++) {
            bh[nt][kc] = *(const short8*)(Wh + nrow + kc * 32 + quad * 8);
            bl[nt][kc] = *(const short8*)(Wl + nrow + kc * 32 + quad * 8);
        }
    }

    for (int i = t; i < 64 * 32; i += 256) {
        const int r = i >> 5, c4 = i & 31;
        const float4 f = ((const float4*)(A + (size_t)(m0 + r) * 128))[c4];
        ushort4 h, l;
        h.x = f2bf(f.x); l.x = f2bf(f.x - b2f(h.x));
        h.y = f2bf(f.y); l.y = f2bf(f.y - b2f(h.y));
        h.z = f2bf(f.z); l.z = f2bf(f.z - b2f(h.z));
        h.w = f2bf(f.w); l.w = f2bf(f.w - b2f(h.w));
        *(ushort4*)(&Ah[r * 136 + c4 * 4]) = h;
        *(ushort4*)(&Al[r * 136 + c4 * 4]) = l;
    }
    __syncthreads();

    f32x4 acc[4][2] = {};
#pragma unroll
    for (int kc = 0; kc < 4; kc++) {
        const int kb = kc * 32 + quad * 8;
        short8 ah[4], al[4];
#pragma unroll
        for (int mt = 0; mt < 4; mt++) {
            ah[mt] = *(const short8*)(&Ah[(mt * 16 + l16) * 136 + kb]);
            al[mt] = *(const short8*)(&Al[(mt * 16 + l16) * 136 + kb]);
        }
#pragma unroll
        for (int mt = 0; mt < 4; mt++)
#pragma unroll
            for (int nt = 0; nt < 2; nt++) {
                acc[mt][nt] = __builtin_amdgcn_mfma_f32_16x16x32_bf16(
                                  ah[mt], bh[nt][kc], acc[mt][nt], 0, 0, 0);
                acc[mt][nt] = __builtin_amdgcn_mfma_f32_16x16x32_bf16(
                                  ah[mt], bl[nt][kc], acc[mt][nt], 0, 0, 0);
                acc[mt][nt] = __builtin_amdgcn_mfma_f32_16x16x32_bf16(
                                  al[mt], bh[nt][kc], acc[mt][nt], 0, 0, 0);
            }
    }

#pragma unroll
    for (int nt = 0; nt < 2; nt++) {
        const int n = n0 + wn + nt * 16 + l16;
        const float bv = (n < nsplit) ? bias0[n] : bias1[n - nsplit];
#pragma unroll
        for (int mt = 0; mt < 4; mt++) {
            const int mb = m0 + mt * 16 + quad * 4;
#pragma unroll
            for (int r = 0; r < 4; r++)
                C[(size_t)(mb + r) * N + n] = acc[mt][nt][r] + bv;
        }
    }
}

// ---------------------------------------------------------------------------
// K2: depthwise 3x3 LEPE conv, 8 w-positions per block.
// grid 8192 = (b, h, wgroup), block 128 (channel).  Each thread caches the
// 3x10 halo for its channel in registers: 30 loads per 8 outputs (was 72).
// ---------------------------------------------------------------------------
__global__ __launch_bounds__(128) void k_conv(
                       const float* __restrict__ qkv2,
                       const float* __restrict__ cw, const float* __restrict__ cb,
                       float* __restrict__ out3)
{
    const int blk = blockIdx.x;
    const int wg = blk & 15;
    const int h = (blk >> 4) & 127;
    const int b = blk >> 11;
    const int c = threadIdx.x;
    const int w0 = wg * 8;
    const int ch = (c < 64) ? (320 + c) : (128 + c - 64);
    const float* src = qkv2 + ch;

    float vals[3][10];
#pragma unroll
    for (int rr = 0; rr < 3; rr++) {
        const int hr = h - 1 + rr;
        const bool hv = (hr >= 0 && hr < 128);
#pragma unroll
        for (int j = 0; j < 10; j++) {
            const int wc = w0 - 1 + j;
            const bool wv = (wc >= 0 && wc < 128);
            vals[rr][j] = (hv && wv)
                ? src[((size_t)b * 16384 + hr * 128 + wc) * 384] : 0.f;
        }
    }
    float wt[9];
#pragma unroll
    for (int i = 0; i < 9; i++) wt[i] = cw[c * 9 + i];
    const float bias = cb[c];

#pragma unroll
    for (int p = 0; p < 8; p++) {
        float acc = bias;
#pragma unroll
        for (int dh = 0; dh < 3; dh++)
#pragma unroll
            for (int dw = 0; dw < 3; dw++)
                acc = fmaf(vals[dh][p + dw], wt[dh * 3 + dw], acc);
        out3[((size_t)b * 16384 + h * 128 + w0 + p) * 128 + c] = acc;
    }
}

// ---------------------------------------------------------------------------
// K3: window attention.  grid 8192 = (b,hr,wr,head), block 64 (query pos)
// adds into out3 channels [0,64)
// ---------------------------------------------------------------------------
__global__ __launch_bounds__(64) void k_win(const float* __restrict__ qkv2,
                                            float* __restrict__ out3)
{
    const int bid = blockIdx.x;
    const int n = bid & 7;
    const int win = bid >> 3;
    const int wr = win & 15;
    const int hr = (win >> 4) & 15;
    const int b = win >> 8;
    const int p = threadIdx.x;
    const int wi = p >> 3, wj = p & 7;
    const int h = hr * 8 + wi, w = wr * 8 + wj;
    const size_t row = ((size_t)b * 16384 + h * 128 + w) * 384;

    __shared__ float kk[64][8];
    __shared__ float vv[64][8];
    float q[8];
#pragma unroll
    for (int d = 0; d < 8; d++) {
        q[d] = qkv2[row + n * 8 + d] * SCALE_F;
        kk[p][d] = qkv2[row + 64 + n * 8 + d];
        vv[p][d] = qkv2[row + 128 + n * 8 + d];
    }
    __syncthreads();

    float s[64];
    float m = -1e30f;
#pragma unroll
    for (int j = 0; j < 64; j++) {
        float a = 0.f;
#pragma unroll
        for (int d = 0; d < 8; d++) a = fmaf(q[d], kk[j][d], a);
        s[j] = a;
        m = fmaxf(m, a);
    }
    float sum = 0.f;
#pragma unroll
    for (int j = 0; j < 64; j++) {
        s[j] = __expf(s[j] - m);
        sum += s[j];
    }
    const float inv = 1.0f / sum;
    float o[8] = {0.f, 0.f, 0.f, 0.f, 0.f, 0.f, 0.f, 0.f};
#pragma unroll
    for (int j = 0; j < 64; j++) {
        const float pj = s[j] * inv;
#pragma unroll
        for (int d = 0; d < 8; d++) o[d] = fmaf(pj, vv[j][d], o[d]);
    }
    const size_t orow = ((size_t)b * 16384 + h * 128 + w) * 128;
#pragma unroll
    for (int d = 0; d < 8; d++) out3[orow + n * 8 + d] += o[d];
}

// ---------------------------------------------------------------------------
// K4: routing scores input, BIT-IDENTICAL to the passing scalar path (frozen).
// ---------------------------------------------------------------------------
__global__ __launch_bounds__(128) void k_scores(const float* __restrict__ x,
                       const float* __restrict__ bw, const float* __restrict__ bb,
                       float* __restrict__ pq, float* __restrict__ pk)
{
    const int r = blockIdx.x;
    const int b = r >> 8;
    const int reg = r & 255;
    const int hr = reg >> 4, wr = reg & 15;
    const int c = threadIdx.x;

    float wreg[64];
#pragma unroll
    for (int k = 0; k < 64; k++) wreg[k] = bw[k * 192 + c];
    const float bias = bb[c];

    __shared__ float xs[64][64];
    for (int i = c; i < 64 * 64; i += 128) {
        const int p = i >> 6, ch = i & 63;
        const int h = hr * 8 + (p >> 3), w = wr * 8 + (p & 7);
        xs[p][ch] = x[((size_t)b * 16384 + h * 128 + w) * 128 + 64 + ch];
    }
    __syncthreads();

    float pool = 0.f;
    for (int p = 0; p < 64; p++) {
        float acc = bias;
#pragma unroll
        for (int k = 0; k < 64; k++) acc = fmaf(xs[p][k], wreg[k], acc);
        pool += acc;
    }
    pool *= (1.0f / 64.0f);
    if (c < 64) pq[(size_t)r * 64 + c] = pool;
    else        pk[(size_t)r * 64 + (c - 64)] = pool;
}

// ---------------------------------------------------------------------------
// K5: routing scores + stable top-4.  grid 1024 = (b, i), block 64  (frozen)
// ---------------------------------------------------------------------------
__global__ __launch_bounds__(64) void k_topk(const float* __restrict__ pq,
                       const float* __restrict__ pk, int* __restrict__ idx)
{
    const int bi = blockIdx.x;
    const int b = bi >> 8;
    const int t = threadIdx.x;
    __shared__ float qrow[64];
    __shared__ float s[256];
    qrow[t] = pq[(size_t)bi * 64 + t];
    __syncthreads();
    for (int j4 = 0; j4 < 4; j4++) {
        const int j = j4 * 64 + t;
        const float* krow = pk + ((size_t)b * 256 + j) * 64;
        float a = 0.f;
#pragma unroll
        for (int c = 0; c < 64; c++) a = fmaf(qrow[c], krow[c], a);
        s[j] = a;
    }
    __syncthreads();
    if (t == 0) {
        int chosen[4];
        for (int sel = 0; sel < 4; sel++) {
            float best = -1e30f;
            int bj = -1;
            for (int j = 0; j < 256; j++) {
                bool skip = false;
                for (int u = 0; u < sel; u++) skip = skip || (chosen[u] == j);
                if (!skip && s[j] > best) { best = s[j]; bj = j; }
            }
            chosen[sel] = bj;
            idx[bi * 4 + sel] = bj;
        }
    }
}

// ---------------------------------------------------------------------------
// K6: gathered BRA attention, 2 waves per block, fast exp.
// ---------------------------------------------------------------------------
__global__ __launch_bounds__(128) void k_bra(const float* __restrict__ qkv2,
                      const int* __restrict__ idx, float* __restrict__ out3)
{
    const int r = blockIdx.x & 255;
    const int n = (blockIdx.x >> 8) & 7;
    const int b = blockIdx.x >> 11;
    const int tid = threadIdx.x;
    const int q = tid & 63;
    const int half = tid >> 6;

    __shared__ float kk[256][8];
    __shared__ float vv[256][8];

    for (int i = tid; i < 512; i += 128) {
        const int isv = (i >= 256);
        const int row = i & 255;
        const int rt = idx[((b << 8) + r) * 4 + (row >> 6)];
        const int p = row & 63;
        const int hh = (rt >> 4) * 8 + (p >> 3);
        const int ww = (rt & 15) * 8 + (p & 7);
        const float* src = qkv2 + ((size_t)b * 16384 + hh * 128 + ww) * 384
                           + (isv ? 320 : 256) + n * 8;
        const float4 f0 = ((const float4*)src)[0];
        const float4 f1 = ((const float4*)src)[1];
        float* dst = isv ? &vv[row][0] : &kk[row][0];
        ((float4*)dst)[0] = f0;
        ((float4*)dst)[1] = f1;
    }

    const int hq = (r >> 4) * 8 + (q >> 3), wq = (r & 15) * 8 + (q & 7);
    const size_t qoff = ((size_t)b * 16384 + hq * 128 + wq) * 384 + 192 + n * 8;
    float qv[8];
    {
        const float4 f0 = ((const float4*)(qkv2 + qoff))[0];
        const float4 f1 = ((const float4*)(qkv2 + qoff))[1];
        qv[0] = f0.x * SCALE_F; qv[1] = f0.y * SCALE_F;
        qv[2] = f0.z * SCALE_F; qv[3] = f0.w * SCALE_F;
        qv[4] = f1.x * SCALE_F; qv[5] = f1.y * SCALE_F;
        qv[6] = f1.z * SCALE_F; qv[7] = f1.w * SCALE_F;
    }
    __syncthreads();

    float m = -1e30f, sum = 0.f;
    float o[8] = {0.f, 0.f, 0.f, 0.f, 0.f, 0.f, 0.f, 0.f};
    const int j0 = half * 128;
    for (int c = 0; c < 4; c++) {
        float s[32];
        float mc = -1e30f;
        const int jb = j0 + c * 32;
#pragma unroll
        for (int j = 0; j < 32; j++) {
            float a = 0.f;
#pragma unroll
            for (int d = 0; d < 8; d++) a = fmaf(qv[d], kk[jb + j][d], a);
            s[j] = a;
            mc = fmaxf(mc, a);
        }
        const float m_new = fmaxf(m, mc);
        const float corr = __expf(m - m_new);
        sum *= corr;
#pragma unroll
        for (int d = 0; d < 8; d++) o[d] *= corr;
#pragma unroll
        for (int j = 0; j < 32; j++) {
            const float e = __expf(s[j] - m_new);
            sum += e;
#pragma unroll
            for (int d = 0; d < 8; d++) o[d] = fmaf(e, vv[jb + j][d], o[d]);
        }
        m = m_new;
    }

    __syncthreads();
    float* st = &kk[0][0];
    if (half == 1) {
        float* p = st + q * 12;
        p[0] = m; p[1] = sum;
#pragma unroll
        for (int d = 0; d < 8; d++) p[2 + d] = o[d];
    }
    __syncthreads();
    if (half == 0) {
        const float* p = st + q * 12;
        const float m1 = p[0], s1 = p[1];
        const float mN = fmaxf(m, m1);
        const float c0 = __expf(m - mN), c1 = __expf(m1 - mN);
        const float inv = 1.0f / (sum * c0 + s1 * c1);
        const size_t orow = ((size_t)b * 16384 + hq * 128 + wq) * 128;
#pragma unroll
        for (int d = 0; d < 8; d++)
            out3[orow + 64 + n * 8 + d] += (o[d] * c0 + p[2 + d] * c1) * inv;
    }
}

// ---------------------------------------------------------------------------
// K9a: channel-attn partial Gram + partial sq-norms.  grid 512 = (bn, chunk),
// block 256 = (d, e).  Reads position-major cqkv (pos, 384).
// ---------------------------------------------------------------------------
__global__ __launch_bounds__(256) void k_cattn_part(const float* __restrict__ cq,
                                                    float* __restrict__ part)
{
    const int bn = blockIdx.x >> 4;
    const int ch = blockIdx.x & 15;
    const int b = bn >> 3, n = bn & 7;
    const int t = threadIdx.x;
    const int d = t >> 4, e = t & 15;
    __shared__ float qs[128][16];
    __shared__ float ks[128][16];
    const float* base = cq + ((size_t)b * 16384 + ch * 1024) * 384;

    float acc = 0.f, nq = 0.f, nk = 0.f;
    for (int l0 = 0; l0 < 1024; l0 += 128) {
        for (int i = t; i < 128 * 32; i += 256) {
            const int pos = i >> 5;
            const int en = i & 31;
            const int col = (en < 16) ? (n * 16 + en) : (128 + n * 16 + en - 16);
            const float v = base[(size_t)(l0 + pos) * 384 + col];
            if (en < 16) qs[pos][en] = v;
            else         ks[pos][en - 16] = v;
        }
        __syncthreads();
#pragma unroll
        for (int l = 0; l < 128; l++) acc = fmaf(qs[l][d], ks[l][e], acc);
#pragma unroll
        for (int l8 = 0; l8 < 8; l8++) {
            const float qv = qs[l8 * 16 + e][d];
            const float kv = ks[l8 * 16 + d][e];
            nq = fmaf(qv, qv, nq);
            nk = fmaf(kv, kv, nk);
        }
        __syncthreads();
    }
    part[((size_t)bn * 16 + ch) * 288 + t] = acc;

    __shared__ float rq[16][17];
    __shared__ float rk[16][17];
    rq[d][e] = nq;
    rk[e][d] = nk;
    __syncthreads();
    if (t < 16) {
        float sq = 0.f, sk = 0.f;
#pragma unroll
        for (int j = 0; j < 16; j++) { sq += rq[t][j]; sk += rk[t][j]; }
        part[((size_t)bn * 16 + ch) * 288 + 256 + t] = sq;
        part[((size_t)bn * 16 + ch) * 288 + 272 + t] = sk;
    }
}

// ---------------------------------------------------------------------------
// K9b: reduce partials, inv-norms, scale, softmax.  grid 32 = bn, block 256
// ---------------------------------------------------------------------------
__global__ __launch_bounds__(256) void k_cattn_red(const float* __restrict__ part,
                        const float* __restrict__ temp, float* __restrict__ cattn)
{
    const int bn = blockIdx.x;
    const int t = threadIdx.x;
    const int d = t >> 4;
    const int e = t & 15;
    float acc = 0.f;
#pragma unroll
    for (int ch = 0; ch < 16; ch++) acc += part[((size_t)bn * 16 + ch) * 288 + t];
    __shared__ float inorm[32];
    if (t < 32) {
        float s = 0.f;
#pragma unroll
        for (int ch = 0; ch < 16; ch++) s += part[((size_t)bn * 16 + ch) * 288 + 256 + t];
        inorm[t] = 1.0f / fmaxf(sqrtf(s), 1e-12f);
    }
    __syncthreads();
    const int n = bn & 7;
    const float scl = inorm[d] * inorm[16 + e] * temp[n];
    __shared__ float S[16][17];
    S[d][e] = acc * scl;
    __syncthreads();
    if (t < 16) {
        float mm = -1e30f;
#pragma unroll
        for (int e2 = 0; e2 < 16; e2++) mm = fmaxf(mm, S[t][e2]);
        float ex[16];
        float ss = 0.f;
#pragma unroll
        for (int e2 = 0; e2 < 16; e2++) {
            ex[e2] = __expf(S[t][e2] - mm);
            ss += ex[e2];
        }
        const float inv = 1.0f / ss;
#pragma unroll
        for (int e2 = 0; e2 < 16; e2++) cattn[(bn * 16 + t) * 16 + e2] = ex[e2] * inv;
    }
}

// ---------------------------------------------------------------------------
// K10: cout = cattn @ cv (position-major cv), written (B, L, 128) into out3
// grid 8192 = (bn, l/64), block 64
// ---------------------------------------------------------------------------
__global__ __launch_bounds__(64) void k_cout(const float* __restrict__ cattn,
                       const float* __restrict__ cq, float* __restrict__ out3)
{
    const int blk = blockIdx.x;
    const int bn = blk >> 8;
    const int b = bn >> 3, n = bn & 7;
    const int l0 = (blk & 255) * 64;
    const int t = threadIdx.x;
    __shared__ float A[16][17];
    for (int i = t; i < 256; i += 64) A[i >> 4][i & 15] = cattn[bn * 256 + i];
    __syncthreads();
    const int pos = l0 + t;
    const float* vp = cq + ((size_t)b * 16384 + pos) * 384 + 256 + n * 16;
    float v[16];
#pragma unroll
    for (int e4 = 0; e4 < 4; e4++) {
        const float4 f = ((const float4*)vp)[e4];
        v[e4 * 4 + 0] = f.x; v[e4 * 4 + 1] = f.y; v[e4 * 4 + 2] = f.z; v[e4 * 4 + 3] = f.w;
    }
    float acc[16];
#pragma unroll
    for (int d = 0; d < 16; d++) acc[d] = 0.f;
#pragma unroll
    for (int e = 0; e < 16; e++) {
#pragma unroll
        for (int d = 0; d < 16; d++) acc[d] = fmaf(A[d][e], v[e], acc[d]);
    }
    float* op = out3 + ((size_t)b * 16384 + pos) * 128 + n * 16;
#pragma unroll
    for (int d4 = 0; d4 < 4; d4++) {
        float4 f;
        f.x = acc[d4 * 4 + 0]; f.y = acc[d4 * 4 + 1]; f.z = acc[d4 * 4 + 2]; f.w = acc[d4 * 4 + 3];
        ((float4*)op)[d4] = f;
    }
}

// ---------------------------------------------------------------------------
extern "C" void kernel_launch(void* const* d_in, const int* in_sizes, int n_in,
                              void* d_out, int out_size, void* d_ws, size_t ws_size,
                              hipStream_t stream)
{
    const float* x       = (const float*)d_in[0];
    const float* wqkv_w  = (const float*)d_in[1];
    const float* wqkv_b  = (const float*)d_in[2];
    const float* bqkv_w  = (const float*)d_in[3];
    const float* bqkv_b  = (const float*)d_in[4];
    const float* lepe_w  = (const float*)d_in[5];
    const float* lepe_b  = (const float*)d_in[6];
    const float* ca_qkv_w = (const float*)d_in[7];
    const float* ca_qkv_b = (const float*)d_in[8];
    const float* ca_temp  = (const float*)d_in[9];
    const float* ca_proj_w = (const float*)d_in[10];
    const float* ca_proj_b = (const float*)d_in[11];

    float* ws = (float*)d_ws;
    float* qkv2 = ws;                         // 65536*384 floats (pos-major)
    float* cqkv = ws;                         // alias (qkv2 dead after k_bra)
    float* out3 = ws + 25165824;              // 65536*128 floats
    float* aux  = out3 + 8388608;             // aux region
    float* pq   = aux;                        // 65536 (dead after k_topk)
    float* pk   = pq + 65536;                 // 65536 (dead after k_topk)
    int*   idx  = (int*)(pk + 65536);         // 4096 ints (dead after k_bra)
    float* part = aux;                        // alias pq..idx: 147456
    float* catn = aux + 147456;               // 8192
    ushort* wt1h = (ushort*)aux;              // aliases aux (dead before k_scores)
    ushort* wt1l = (ushort*)(aux + 24576);
    float* tail = aux + 155648;
    ushort* wt2h = (ushort*)tail;
    ushort* wt2l = (ushort*)(tail + 24576);
    ushort* wt3h = (ushort*)(tail + 49152);
    ushort* wt3l = (ushort*)(tail + 57344);

    k_pack<<<896, 128, 0, stream>>>(wqkv_w, bqkv_w, ca_qkv_w, ca_proj_w,
                                    wt1h, wt1l, wt2h, wt2l, wt3h, wt3l);
    k_gemm<<<dim3(1024, 3), 256, 0, stream>>>(x, wt1h, wt1l,
                                              wqkv_b, bqkv_b, 192, qkv2, 384);
    k_conv<<<8192, 128, 0, stream>>>(qkv2, lepe_w, lepe_b, out3);
    k_win<<<8192, 64, 0, stream>>>(qkv2, out3);
    k_scores<<<1024, 128, 0, stream>>>(x, bqkv_w, bqkv_b, pq, pk);
    k_topk<<<1024, 64, 0, stream>>>(pq, pk, idx);
    k_bra<<<8192, 128, 0, stream>>>(qkv2, idx, out3);
    k_gemm<<<dim3(1024, 3), 256, 0, stream>>>(out3, wt2h, wt2l,
                                              ca_qkv_b, ca_qkv_b, 384, cqkv, 384);
    k_cattn_part<<<512, 256, 0, stream>>>(cqkv, part);
    k_cattn_red<<<32, 256, 0, stream>>>(part, ca_temp, catn);
    k_cout<<<8192, 64, 0, stream>>>(catn, cqkv, out3);
    k_gemm<<<dim3(1024, 1), 256, 0, stream>>>(out3, wt3h, wt3l,
                                              ca_proj_b, ca_proj_b, 128,
                                              (float*)d_out, 128);
}

// Round 13
// 522.774 us; speedup vs baseline: 7.0041x; 1.0286x over previous
//
#include <hip/hip_runtime.h>
#include <math.h>

#define SCALE_F 0.08838834764831843f

typedef __attribute__((ext_vector_type(8))) short short8;
typedef __attribute__((ext_vector_type(4))) float f32x4;

__device__ __forceinline__ ushort f2bf(float f) {
    unsigned u = __float_as_uint(f);
    u = (u + 0x7fff + ((u >> 16) & 1)) >> 16;   // RNE
    return (ushort)u;
}
__device__ __forceinline__ float b2f(ushort h) {
    return __uint_as_float(((unsigned)h) << 16);
}

// ---------------------------------------------------------------------------
// K0: pack weights to bf16 hi/lo pairs, transposed to (N,128) k-contiguous.
// ---------------------------------------------------------------------------
__global__ __launch_bounds__(128) void k_pack(
    const float* __restrict__ ww, const float* __restrict__ bw,
    const float* __restrict__ qw, const float* __restrict__ pw,
    ushort* __restrict__ wt1h, ushort* __restrict__ wt1l,
    ushort* __restrict__ wt2h, ushort* __restrict__ wt2l,
    ushort* __restrict__ wt3h, ushort* __restrict__ wt3l)
{
    const int blk = blockIdx.x;
    const int t = threadIdx.x;
    float v;
    ushort *dh, *dl;
    int off;
    if (blk < 384) {
        const int n = blk;
        if (n < 192) v = (t < 64) ? ww[t * 192 + n] : 0.f;
        else         v = (t >= 64) ? bw[(t - 64) * 192 + (n - 192)] : 0.f;
        dh = wt1h; dl = wt1l; off = n * 128 + t;
    } else if (blk < 768) {
        const int n = blk - 384;
        v = qw[t * 384 + n];
        dh = wt2h; dl = wt2l; off = n * 128 + t;
    } else {
        const int n = blk - 768;
        v = pw[t * 128 + n];
        dh = wt3h; dl = wt3l; off = n * 128 + t;
    }
    const ushort h = f2bf(v);
    dh[off] = h;
    dl[off] = f2bf(v - b2f(h));
}

// ---------------------------------------------------------------------------
// K-GEMM (split precision): C = A(M x 128 fp32) @ W^T + bias as
// ah*bh + ah*bl + al*bh in bf16 MFMA (fp32-accurate to ~4e-6 rel).
// ---------------------------------------------------------------------------
__global__ __launch_bounds__(256, 2) void k_gemm(
    const float* __restrict__ A,
    const ushort* __restrict__ Wh, const ushort* __restrict__ Wl,
    const float* __restrict__ bias0, const float* __restrict__ bias1, int nsplit,
    float* __restrict__ C, int N)
{
    __shared__ ushort Ah[64 * 136];
    __shared__ ushort Al[64 * 136];
    const int m0 = blockIdx.x * 64;
    const int n0 = blockIdx.y * 128;
    const int t = threadIdx.x;
    const int wave = t >> 6, lane = t & 63;
    const int quad = lane >> 4, l16 = lane & 15;
    const int wn = wave * 32;

    short8 bh[2][4], bl[2][4];
#pragma unroll
    for (int nt = 0; nt < 2; nt++) {
        const size_t nrow = (size_t)(n0 + wn + nt * 16 + l16) * 128;
#pragma unroll
        for (int kc = 0; kc < 4; kc++) {
            bh[nt][kc] = *(const short8*)(Wh + nrow + kc * 32 + quad * 8);
            bl[nt][kc] = *(const short8*)(Wl + nrow + kc * 32 + quad * 8);
        }
    }

    for (int i = t; i < 64 * 32; i += 256) {
        const int r = i >> 5, c4 = i & 31;
        const float4 f = ((const float4*)(A + (size_t)(m0 + r) * 128))[c4];
        ushort4 h, l;
        h.x = f2bf(f.x); l.x = f2bf(f.x - b2f(h.x));
        h.y = f2bf(f.y); l.y = f2bf(f.y - b2f(h.y));
        h.z = f2bf(f.z); l.z = f2bf(f.z - b2f(h.z));
        h.w = f2bf(f.w); l.w = f2bf(f.w - b2f(h.w));
        *(ushort4*)(&Ah[r * 136 + c4 * 4]) = h;
        *(ushort4*)(&Al[r * 136 + c4 * 4]) = l;
    }
    __syncthreads();

    f32x4 acc[4][2] = {};
#pragma unroll
    for (int kc = 0; kc < 4; kc++) {
        const int kb = kc * 32 + quad * 8;
        short8 ah[4], al[4];
#pragma unroll
        for (int mt = 0; mt < 4; mt++) {
            ah[mt] = *(const short8*)(&Ah[(mt * 16 + l16) * 136 + kb]);
            al[mt] = *(const short8*)(&Al[(mt * 16 + l16) * 136 + kb]);
        }
#pragma unroll
        for (int mt = 0; mt < 4; mt++)
#pragma unroll
            for (int nt = 0; nt < 2; nt++) {
                acc[mt][nt] = __builtin_amdgcn_mfma_f32_16x16x32_bf16(
                                  ah[mt], bh[nt][kc], acc[mt][nt], 0, 0, 0);
                acc[mt][nt] = __builtin_amdgcn_mfma_f32_16x16x32_bf16(
                                  ah[mt], bl[nt][kc], acc[mt][nt], 0, 0, 0);
                acc[mt][nt] = __builtin_amdgcn_mfma_f32_16x16x32_bf16(
                                  al[mt], bh[nt][kc], acc[mt][nt], 0, 0, 0);
            }
    }

#pragma unroll
    for (int nt = 0; nt < 2; nt++) {
        const int n = n0 + wn + nt * 16 + l16;
        const float bv = (n < nsplit) ? bias0[n] : bias1[n - nsplit];
#pragma unroll
        for (int mt = 0; mt < 4; mt++) {
            const int mb = m0 + mt * 16 + quad * 4;
#pragma unroll
            for (int r = 0; r < 4; r++)
                C[(size_t)(mb + r) * N + n] = acc[mt][nt][r] + bv;
        }
    }
}

// ---------------------------------------------------------------------------
// K2: depthwise 3x3 LEPE conv, 8 w-positions per block.
// ---------------------------------------------------------------------------
__global__ __launch_bounds__(128) void k_conv(
                       const float* __restrict__ qkv2,
                       const float* __restrict__ cw, const float* __restrict__ cb,
                       float* __restrict__ out3)
{
    const int blk = blockIdx.x;
    const int wg = blk & 15;
    const int h = (blk >> 4) & 127;
    const int b = blk >> 11;
    const int c = threadIdx.x;
    const int w0 = wg * 8;
    const int ch = (c < 64) ? (320 + c) : (128 + c - 64);
    const float* src = qkv2 + ch;

    float vals[3][10];
#pragma unroll
    for (int rr = 0; rr < 3; rr++) {
        const int hr = h - 1 + rr;
        const bool hv = (hr >= 0 && hr < 128);
#pragma unroll
        for (int j = 0; j < 10; j++) {
            const int wc = w0 - 1 + j;
            const bool wv = (wc >= 0 && wc < 128);
            vals[rr][j] = (hv && wv)
                ? src[((size_t)b * 16384 + hr * 128 + wc) * 384] : 0.f;
        }
    }
    float wt[9];
#pragma unroll
    for (int i = 0; i < 9; i++) wt[i] = cw[c * 9 + i];
    const float bias = cb[c];

#pragma unroll
    for (int p = 0; p < 8; p++) {
        float acc = bias;
#pragma unroll
        for (int dh = 0; dh < 3; dh++)
#pragma unroll
            for (int dw = 0; dw < 3; dw++)
                acc = fmaf(vals[dh][p + dw], wt[dh * 3 + dw], acc);
        out3[((size_t)b * 16384 + h * 128 + w0 + p) * 128 + c] = acc;
    }
}

// ---------------------------------------------------------------------------
// K3: window attention, TWO windows (bids) per block (one per wave).
// grid 4096, block 128.  wave = bid parity; adds into out3 channels [0,64)
// ---------------------------------------------------------------------------
__global__ __launch_bounds__(128) void k_win(const float* __restrict__ qkv2,
                                             float* __restrict__ out3)
{
    const int half = threadIdx.x >> 6;
    const int bid = blockIdx.x * 2 + half;
    const int n = bid & 7;
    const int win = bid >> 3;
    const int wr = win & 15;
    const int hr = (win >> 4) & 15;
    const int b = win >> 8;
    const int p = threadIdx.x & 63;
    const int wi = p >> 3, wj = p & 7;
    const int h = hr * 8 + wi, w = wr * 8 + wj;
    const size_t row = ((size_t)b * 16384 + h * 128 + w) * 384;

    __shared__ float kk[2][64][8];
    __shared__ float vv[2][64][8];
    float q[8];
#pragma unroll
    for (int d = 0; d < 8; d++) {
        q[d] = qkv2[row + n * 8 + d] * SCALE_F;
        kk[half][p][d] = qkv2[row + 64 + n * 8 + d];
        vv[half][p][d] = qkv2[row + 128 + n * 8 + d];
    }
    __syncthreads();

    float s[64];
    float m = -1e30f;
#pragma unroll
    for (int j = 0; j < 64; j++) {
        float a = 0.f;
#pragma unroll
        for (int d = 0; d < 8; d++) a = fmaf(q[d], kk[half][j][d], a);
        s[j] = a;
        m = fmaxf(m, a);
    }
    float sum = 0.f;
#pragma unroll
    for (int j = 0; j < 64; j++) {
        s[j] = __expf(s[j] - m);
        sum += s[j];
    }
    const float inv = 1.0f / sum;
    float o[8] = {0.f, 0.f, 0.f, 0.f, 0.f, 0.f, 0.f, 0.f};
#pragma unroll
    for (int j = 0; j < 64; j++) {
        const float pj = s[j] * inv;
#pragma unroll
        for (int d = 0; d < 8; d++) o[d] = fmaf(pj, vv[half][j][d], o[d]);
    }
    const size_t orow = ((size_t)b * 16384 + h * 128 + w) * 128;
#pragma unroll
    for (int d = 0; d < 8; d++) out3[orow + n * 8 + d] += o[d];
}

// ---------------------------------------------------------------------------
// K4: routing scores input, BIT-IDENTICAL to the passing scalar path (frozen).
// ---------------------------------------------------------------------------
__global__ __launch_bounds__(128) void k_scores(const float* __restrict__ x,
                       const float* __restrict__ bw, const float* __restrict__ bb,
                       float* __restrict__ pq, float* __restrict__ pk)
{
    const int r = blockIdx.x;
    const int b = r >> 8;
    const int reg = r & 255;
    const int hr = reg >> 4, wr = reg & 15;
    const int c = threadIdx.x;

    float wreg[64];
#pragma unroll
    for (int k = 0; k < 64; k++) wreg[k] = bw[k * 192 + c];
    const float bias = bb[c];

    __shared__ float xs[64][64];
    for (int i = c; i < 64 * 64; i += 128) {
        const int p = i >> 6, ch = i & 63;
        const int h = hr * 8 + (p >> 3), w = wr * 8 + (p & 7);
        xs[p][ch] = x[((size_t)b * 16384 + h * 128 + w) * 128 + 64 + ch];
    }
    __syncthreads();

    float pool = 0.f;
    for (int p = 0; p < 64; p++) {
        float acc = bias;
#pragma unroll
        for (int k = 0; k < 64; k++) acc = fmaf(xs[p][k], wreg[k], acc);
        pool += acc;
    }
    pool *= (1.0f / 64.0f);
    if (c < 64) pq[(size_t)r * 64 + c] = pool;
    else        pk[(size_t)r * 64 + (c - 64)] = pool;
}

// ---------------------------------------------------------------------------
// K5: routing scores + stable top-4.  (frozen)
// ---------------------------------------------------------------------------
__global__ __launch_bounds__(64) void k_topk(const float* __restrict__ pq,
                       const float* __restrict__ pk, int* __restrict__ idx)
{
    const int bi = blockIdx.x;
    const int b = bi >> 8;
    const int t = threadIdx.x;
    __shared__ float qrow[64];
    __shared__ float s[256];
    qrow[t] = pq[(size_t)bi * 64 + t];
    __syncthreads();
    for (int j4 = 0; j4 < 4; j4++) {
        const int j = j4 * 64 + t;
        const float* krow = pk + ((size_t)b * 256 + j) * 64;
        float a = 0.f;
#pragma unroll
        for (int c = 0; c < 64; c++) a = fmaf(qrow[c], krow[c], a);
        s[j] = a;
    }
    __syncthreads();
    if (t == 0) {
        int chosen[4];
        for (int sel = 0; sel < 4; sel++) {
            float best = -1e30f;
            int bj = -1;
            for (int j = 0; j < 256; j++) {
                bool skip = false;
                for (int u = 0; u < sel; u++) skip = skip || (chosen[u] == j);
                if (!skip && s[j] > best) { best = s[j]; bj = j; }
            }
            chosen[sel] = bj;
            idx[bi * 4 + sel] = bj;
        }
    }
}

// ---------------------------------------------------------------------------
// K6: gathered BRA attention — ROUND-10 version (verified passing).
// ---------------------------------------------------------------------------
__global__ __launch_bounds__(128) void k_bra(const float* __restrict__ qkv2,
                      const int* __restrict__ idx, float* __restrict__ out3)
{
    const int r = blockIdx.x & 255;
    const int n = (blockIdx.x >> 8) & 7;
    const int b = blockIdx.x >> 11;
    const int tid = threadIdx.x;
    const int q = tid & 63;
    const int half = tid >> 6;

    __shared__ float kk[256][8];
    __shared__ float vv[256][8];

    for (int i = tid; i < 512; i += 128) {
        const int isv = (i >= 256);
        const int row = i & 255;
        const int rt = idx[((b << 8) + r) * 4 + (row >> 6)];
        const int p = row & 63;
        const int hh = (rt >> 4) * 8 + (p >> 3);
        const int ww = (rt & 15) * 8 + (p & 7);
        const float* src = qkv2 + ((size_t)b * 16384 + hh * 128 + ww) * 384
                           + (isv ? 320 : 256) + n * 8;
        const float4 f0 = ((const float4*)src)[0];
        const float4 f1 = ((const float4*)src)[1];
        float* dst = isv ? &vv[row][0] : &kk[row][0];
        ((float4*)dst)[0] = f0;
        ((float4*)dst)[1] = f1;
    }

    const int hq = (r >> 4) * 8 + (q >> 3), wq = (r & 15) * 8 + (q & 7);
    const size_t qoff = ((size_t)b * 16384 + hq * 128 + wq) * 384 + 192 + n * 8;
    float qv[8];
    {
        const float4 f0 = ((const float4*)(qkv2 + qoff))[0];
        const float4 f1 = ((const float4*)(qkv2 + qoff))[1];
        qv[0] = f0.x * SCALE_F; qv[1] = f0.y * SCALE_F;
        qv[2] = f0.z * SCALE_F; qv[3] = f0.w * SCALE_F;
        qv[4] = f1.x * SCALE_F; qv[5] = f1.y * SCALE_F;
        qv[6] = f1.z * SCALE_F; qv[7] = f1.w * SCALE_F;
    }
    __syncthreads();

    float m = -1e30f, sum = 0.f;
    float o[8] = {0.f, 0.f, 0.f, 0.f, 0.f, 0.f, 0.f, 0.f};
    const int j0 = half * 128;
    for (int c = 0; c < 4; c++) {
        float s[32];
        float mc = -1e30f;
        const int jb = j0 + c * 32;
#pragma unroll
        for (int j = 0; j < 32; j++) {
            float a = 0.f;
#pragma unroll
            for (int d = 0; d < 8; d++) a = fmaf(qv[d], kk[jb + j][d], a);
            s[j] = a;
            mc = fmaxf(mc, a);
        }
        const float m_new = fmaxf(m, mc);
        const float corr = __expf(m - m_new);
        sum *= corr;
#pragma unroll
        for (int d = 0; d < 8; d++) o[d] *= corr;
#pragma unroll
        for (int j = 0; j < 32; j++) {
            const float e = __expf(s[j] - m_new);
            sum += e;
#pragma unroll
            for (int d = 0; d < 8; d++) o[d] = fmaf(e, vv[jb + j][d], o[d]);
        }
        m = m_new;
    }

    __syncthreads();
    float* st = &kk[0][0];
    if (half == 1) {
        float* p = st + q * 12;
        p[0] = m; p[1] = sum;
#pragma unroll
        for (int d = 0; d < 8; d++) p[2 + d] = o[d];
    }
    __syncthreads();
    if (half == 0) {
        const float* p = st + q * 12;
        const float m1 = p[0], s1 = p[1];
        const float mN = fmaxf(m, m1);
        const float c0 = __expf(m - mN), c1 = __expf(m1 - mN);
        const float inv = 1.0f / (sum * c0 + s1 * c1);
        const size_t orow = ((size_t)b * 16384 + hq * 128 + wq) * 128;
#pragma unroll
        for (int d = 0; d < 8; d++)
            out3[orow + 64 + n * 8 + d] += (o[d] * c0 + p[2 + d] * c1) * inv;
    }
}

// ---------------------------------------------------------------------------
// K9a: channel-attn partial Gram + partial sq-norms.
// ---------------------------------------------------------------------------
__global__ __launch_bounds__(256) void k_cattn_part(const float* __restrict__ cq,
                                                    float* __restrict__ part)
{
    const int bn = blockIdx.x >> 4;
    const int ch = blockIdx.x & 15;
    const int b = bn >> 3, n = bn & 7;
    const int t = threadIdx.x;
    const int d = t >> 4, e = t & 15;
    __shared__ float qs[128][16];
    __shared__ float ks[128][16];
    const float* base = cq + ((size_t)b * 16384 + ch * 1024) * 384;

    float acc = 0.f, nq = 0.f, nk = 0.f;
    for (int l0 = 0; l0 < 1024; l0 += 128) {
        for (int i = t; i < 128 * 32; i += 256) {
            const int pos = i >> 5;
            const int en = i & 31;
            const int col = (en < 16) ? (n * 16 + en) : (128 + n * 16 + en - 16);
            const float v = base[(size_t)(l0 + pos) * 384 + col];
            if (en < 16) qs[pos][en] = v;
            else         ks[pos][en - 16] = v;
        }
        __syncthreads();
#pragma unroll
        for (int l = 0; l < 128; l++) acc = fmaf(qs[l][d], ks[l][e], acc);
#pragma unroll
        for (int l8 = 0; l8 < 8; l8++) {
            const float qv = qs[l8 * 16 + e][d];
            const float kv = ks[l8 * 16 + d][e];
            nq = fmaf(qv, qv, nq);
            nk = fmaf(kv, kv, nk);
        }
        __syncthreads();
    }
    part[((size_t)bn * 16 + ch) * 288 + t] = acc;

    __shared__ float rq[16][17];
    __shared__ float rk[16][17];
    rq[d][e] = nq;
    rk[e][d] = nk;
    __syncthreads();
    if (t < 16) {
        float sq = 0.f, sk = 0.f;
#pragma unroll
        for (int j = 0; j < 16; j++) { sq += rq[t][j]; sk += rk[t][j]; }
        part[((size_t)bn * 16 + ch) * 288 + 256 + t] = sq;
        part[((size_t)bn * 16 + ch) * 288 + 272 + t] = sk;
    }
}

// ---------------------------------------------------------------------------
// K9b: reduce partials, inv-norms, scale, softmax.  grid 32 = bn, block 256
// ---------------------------------------------------------------------------
__global__ __launch_bounds__(256) void k_cattn_red(const float* __restrict__ part,
                        const float* __restrict__ temp, float* __restrict__ cattn)
{
    const int bn = blockIdx.x;
    const int t = threadIdx.x;
    const int d = t >> 4;
    const int e = t & 15;
    float acc = 0.f;
#pragma unroll
    for (int ch = 0; ch < 16; ch++) acc += part[((size_t)bn * 16 + ch) * 288 + t];
    __shared__ float inorm[32];
    if (t < 32) {
        float s = 0.f;
#pragma unroll
        for (int ch = 0; ch < 16; ch++) s += part[((size_t)bn * 16 + ch) * 288 + 256 + t];
        inorm[t] = 1.0f / fmaxf(sqrtf(s), 1e-12f);
    }
    __syncthreads();
    const int n = bn & 7;
    const float scl = inorm[d] * inorm[16 + e] * temp[n];
    __shared__ float S[16][17];
    S[d][e] = acc * scl;
    __syncthreads();
    if (t < 16) {
        float mm = -1e30f;
#pragma unroll
        for (int e2 = 0; e2 < 16; e2++) mm = fmaxf(mm, S[t][e2]);
        float ex[16];
        float ss = 0.f;
#pragma unroll
        for (int e2 = 0; e2 < 16; e2++) {
            ex[e2] = __expf(S[t][e2] - mm);
            ss += ex[e2];
        }
        const float inv = 1.0f / ss;
#pragma unroll
        for (int e2 = 0; e2 < 16; e2++) cattn[(bn * 16 + t) * 16 + e2] = ex[e2] * inv;
    }
}

// ---------------------------------------------------------------------------
// K10: cout = cattn @ cv (position-major cv), written (B, L, 128) into out3
// grid 8192 = (bn, l/64), block 64   — ROUND-10 version (verified passing)
// ---------------------------------------------------------------------------
__global__ __launch_bounds__(64) void k_cout(const float* __restrict__ cattn,
                       const float* __restrict__ cq, float* __restrict__ out3)
{
    const int blk = blockIdx.x;
    const int bn = blk >> 8;
    const int b = bn >> 3, n = bn & 7;
    const int l0 = (blk & 255) * 64;
    const int t = threadIdx.x;
    __shared__ float A[16][17];
    for (int i = t; i < 256; i += 64) A[i >> 4][i & 15] = cattn[bn * 256 + i];
    __syncthreads();
    const int pos = l0 + t;
    const float* vp = cq + ((size_t)b * 16384 + pos) * 384 + 256 + n * 16;
    float v[16];
#pragma unroll
    for (int e4 = 0; e4 < 4; e4++) {
        const float4 f = ((const float4*)vp)[e4];
        v[e4 * 4 + 0] = f.x; v[e4 * 4 + 1] = f.y; v[e4 * 4 + 2] = f.z; v[e4 * 4 + 3] = f.w;
    }
    float acc[16];
#pragma unroll
    for (int d = 0; d < 16; d++) acc[d] = 0.f;
#pragma unroll
    for (int e = 0; e < 16; e++) {
#pragma unroll
        for (int d = 0; d < 16; d++) acc[d] = fmaf(A[d][e], v[e], acc[d]);
    }
    float* op = out3 + ((size_t)b * 16384 + pos) * 128 + n * 16;
#pragma unroll
    for (int d4 = 0; d4 < 4; d4++) {
        float4 f;
        f.x = acc[d4 * 4 + 0]; f.y = acc[d4 * 4 + 1]; f.z = acc[d4 * 4 + 2]; f.w = acc[d4 * 4 + 3];
        ((float4*)op)[d4] = f;
    }
}

// ---------------------------------------------------------------------------
extern "C" void kernel_launch(void* const* d_in, const int* in_sizes, int n_in,
                              void* d_out, int out_size, void* d_ws, size_t ws_size,
                              hipStream_t stream)
{
    const float* x       = (const float*)d_in[0];
    const float* wqkv_w  = (const float*)d_in[1];
    const float* wqkv_b  = (const float*)d_in[2];
    const float* bqkv_w  = (const float*)d_in[3];
    const float* bqkv_b  = (const float*)d_in[4];
    const float* lepe_w  = (const float*)d_in[5];
    const float* lepe_b  = (const float*)d_in[6];
    const float* ca_qkv_w = (const float*)d_in[7];
    const float* ca_qkv_b = (const float*)d_in[8];
    const float* ca_temp  = (const float*)d_in[9];
    const float* ca_proj_w = (const float*)d_in[10];
    const float* ca_proj_b = (const float*)d_in[11];

    float* ws = (float*)d_ws;
    float* qkv2 = ws;                         // 65536*384 floats (pos-major)
    float* cqkv = ws;                         // alias (qkv2 dead after k_bra)
    float* out3 = ws + 25165824;              // 65536*128 floats
    float* aux  = out3 + 8388608;             // aux region
    float* pq   = aux;                        // 65536 (dead after k_topk)
    float* pk   = pq + 65536;                 // 65536 (dead after k_topk)
    int*   idx  = (int*)(pk + 65536);         // 4096 ints (dead after k_bra)
    float* part = aux;                        // alias pq..idx: 147456
    float* catn = aux + 147456;               // 8192
    ushort* wt1h = (ushort*)aux;              // aliases aux (dead before k_scores)
    ushort* wt1l = (ushort*)(aux + 24576);
    float* tail = aux + 155648;
    ushort* wt2h = (ushort*)tail;
    ushort* wt2l = (ushort*)(tail + 24576);
    ushort* wt3h = (ushort*)(tail + 49152);
    ushort* wt3l = (ushort*)(tail + 57344);

    k_pack<<<896, 128, 0, stream>>>(wqkv_w, bqkv_w, ca_qkv_w, ca_proj_w,
                                    wt1h, wt1l, wt2h, wt2l, wt3h, wt3l);
    k_gemm<<<dim3(1024, 3), 256, 0, stream>>>(x, wt1h, wt1l,
                                              wqkv_b, bqkv_b, 192, qkv2, 384);
    k_conv<<<8192, 128, 0, stream>>>(qkv2, lepe_w, lepe_b, out3);
    k_win<<<4096, 128, 0, stream>>>(qkv2, out3);
    k_scores<<<1024, 128, 0, stream>>>(x, bqkv_w, bqkv_b, pq, pk);
    k_topk<<<1024, 64, 0, stream>>>(pq, pk, idx);
    k_bra<<<8192, 128, 0, stream>>>(qkv2, idx, out3);
    k_gemm<<<dim3(1024, 3), 256, 0, stream>>>(out3, wt2h, wt2l,
                                              ca_qkv_b, ca_qkv_b, 384, cqkv, 384);
    k_cattn_part<<<512, 256, 0, stream>>>(cqkv, part);
    k_cattn_red<<<32, 256, 0, stream>>>(part, ca_temp, catn);
    k_cout<<<8192, 64, 0, stream>>>(catn, cqkv, out3);
    k_gemm<<<dim3(1024, 1), 256, 0, stream>>>(out3, wt3h, wt3l,
                                              ca_proj_b, ca_proj_b, 128,
                                              (float*)d_out, 128);
}

// Round 14
// 504.688 us; speedup vs baseline: 7.2551x; 1.0358x over previous
//
#include <hip/hip_runtime.h>
#include <math.h>

#define SCALE_F 0.08838834764831843f

typedef __attribute__((ext_vector_type(8))) short short8;
typedef __attribute__((ext_vector_type(4))) float f32x4;

__device__ __forceinline__ ushort f2bf(float f) {
    unsigned u = __float_as_uint(f);
    u = (u + 0x7fff + ((u >> 16) & 1)) >> 16;   // RNE
    return (ushort)u;
}
__device__ __forceinline__ float b2f(ushort h) {
    return __uint_as_float(((unsigned)h) << 16);
}

// ---------------------------------------------------------------------------
// K0: pack weights to bf16 hi/lo pairs, transposed to (N,128) k-contiguous.
// ---------------------------------------------------------------------------
__global__ __launch_bounds__(128) void k_pack(
    const float* __restrict__ ww, const float* __restrict__ bw,
    const float* __restrict__ qw, const float* __restrict__ pw,
    ushort* __restrict__ wt1h, ushort* __restrict__ wt1l,
    ushort* __restrict__ wt2h, ushort* __restrict__ wt2l,
    ushort* __restrict__ wt3h, ushort* __restrict__ wt3l)
{
    const int blk = blockIdx.x;
    const int t = threadIdx.x;
    float v;
    ushort *dh, *dl;
    int off;
    if (blk < 384) {
        const int n = blk;
        if (n < 192) v = (t < 64) ? ww[t * 192 + n] : 0.f;
        else         v = (t >= 64) ? bw[(t - 64) * 192 + (n - 192)] : 0.f;
        dh = wt1h; dl = wt1l; off = n * 128 + t;
    } else if (blk < 768) {
        const int n = blk - 384;
        v = qw[t * 384 + n];
        dh = wt2h; dl = wt2l; off = n * 128 + t;
    } else {
        const int n = blk - 768;
        v = pw[t * 128 + n];
        dh = wt3h; dl = wt3l; off = n * 128 + t;
    }
    const ushort h = f2bf(v);
    dh[off] = h;
    dl[off] = f2bf(v - b2f(h));
}

// ---------------------------------------------------------------------------
// K-GEMM (split precision): C = A(M x 128 fp32) @ W^T + bias as
// ah*bh + ah*bl + al*bh in bf16 MFMA (fp32-accurate to ~4e-6 rel).
// ---------------------------------------------------------------------------
__global__ __launch_bounds__(256, 2) void k_gemm(
    const float* __restrict__ A,
    const ushort* __restrict__ Wh, const ushort* __restrict__ Wl,
    const float* __restrict__ bias0, const float* __restrict__ bias1, int nsplit,
    float* __restrict__ C, int N)
{
    __shared__ ushort Ah[64 * 136];
    __shared__ ushort Al[64 * 136];
    const int m0 = blockIdx.x * 64;
    const int n0 = blockIdx.y * 128;
    const int t = threadIdx.x;
    const int wave = t >> 6, lane = t & 63;
    const int quad = lane >> 4, l16 = lane & 15;
    const int wn = wave * 32;

    short8 bh[2][4], bl[2][4];
#pragma unroll
    for (int nt = 0; nt < 2; nt++) {
        const size_t nrow = (size_t)(n0 + wn + nt * 16 + l16) * 128;
#pragma unroll
        for (int kc = 0; kc < 4; kc++) {
            bh[nt][kc] = *(const short8*)(Wh + nrow + kc * 32 + quad * 8);
            bl[nt][kc] = *(const short8*)(Wl + nrow + kc * 32 + quad * 8);
        }
    }

    for (int i = t; i < 64 * 32; i += 256) {
        const int r = i >> 5, c4 = i & 31;
        const float4 f = ((const float4*)(A + (size_t)(m0 + r) * 128))[c4];
        ushort4 h, l;
        h.x = f2bf(f.x); l.x = f2bf(f.x - b2f(h.x));
        h.y = f2bf(f.y); l.y = f2bf(f.y - b2f(h.y));
        h.z = f2bf(f.z); l.z = f2bf(f.z - b2f(h.z));
        h.w = f2bf(f.w); l.w = f2bf(f.w - b2f(h.w));
        *(ushort4*)(&Ah[r * 136 + c4 * 4]) = h;
        *(ushort4*)(&Al[r * 136 + c4 * 4]) = l;
    }
    __syncthreads();

    f32x4 acc[4][2] = {};
#pragma unroll
    for (int kc = 0; kc < 4; kc++) {
        const int kb = kc * 32 + quad * 8;
        short8 ah[4], al[4];
#pragma unroll
        for (int mt = 0; mt < 4; mt++) {
            ah[mt] = *(const short8*)(&Ah[(mt * 16 + l16) * 136 + kb]);
            al[mt] = *(const short8*)(&Al[(mt * 16 + l16) * 136 + kb]);
        }
#pragma unroll
        for (int mt = 0; mt < 4; mt++)
#pragma unroll
            for (int nt = 0; nt < 2; nt++) {
                acc[mt][nt] = __builtin_amdgcn_mfma_f32_16x16x32_bf16(
                                  ah[mt], bh[nt][kc], acc[mt][nt], 0, 0, 0);
                acc[mt][nt] = __builtin_amdgcn_mfma_f32_16x16x32_bf16(
                                  ah[mt], bl[nt][kc], acc[mt][nt], 0, 0, 0);
                acc[mt][nt] = __builtin_amdgcn_mfma_f32_16x16x32_bf16(
                                  al[mt], bh[nt][kc], acc[mt][nt], 0, 0, 0);
            }
    }

#pragma unroll
    for (int nt = 0; nt < 2; nt++) {
        const int n = n0 + wn + nt * 16 + l16;
        const float bv = (n < nsplit) ? bias0[n] : bias1[n - nsplit];
#pragma unroll
        for (int mt = 0; mt < 4; mt++) {
            const int mb = m0 + mt * 16 + quad * 4;
#pragma unroll
            for (int r = 0; r < 4; r++)
                C[(size_t)(mb + r) * N + n] = acc[mt][nt][r] + bv;
        }
    }
}

// ---------------------------------------------------------------------------
// K2: depthwise 3x3 LEPE conv, 8 w-positions per block.
// ---------------------------------------------------------------------------
__global__ __launch_bounds__(128) void k_conv(
                       const float* __restrict__ qkv2,
                       const float* __restrict__ cw, const float* __restrict__ cb,
                       float* __restrict__ out3)
{
    const int blk = blockIdx.x;
    const int wg = blk & 15;
    const int h = (blk >> 4) & 127;
    const int b = blk >> 11;
    const int c = threadIdx.x;
    const int w0 = wg * 8;
    const int ch = (c < 64) ? (320 + c) : (128 + c - 64);
    const float* src = qkv2 + ch;

    float vals[3][10];
#pragma unroll
    for (int rr = 0; rr < 3; rr++) {
        const int hr = h - 1 + rr;
        const bool hv = (hr >= 0 && hr < 128);
#pragma unroll
        for (int j = 0; j < 10; j++) {
            const int wc = w0 - 1 + j;
            const bool wv = (wc >= 0 && wc < 128);
            vals[rr][j] = (hv && wv)
                ? src[((size_t)b * 16384 + hr * 128 + wc) * 384] : 0.f;
        }
    }
    float wt[9];
#pragma unroll
    for (int i = 0; i < 9; i++) wt[i] = cw[c * 9 + i];
    const float bias = cb[c];

#pragma unroll
    for (int p = 0; p < 8; p++) {
        float acc = bias;
#pragma unroll
        for (int dh = 0; dh < 3; dh++)
#pragma unroll
            for (int dw = 0; dw < 3; dw++)
                acc = fmaf(vals[dh][p + dw], wt[dh * 3 + dw], acc);
        out3[((size_t)b * 16384 + h * 128 + w0 + p) * 128 + c] = acc;
    }
}

// ---------------------------------------------------------------------------
// K3: window attention, TWO windows (bids) per block (one per wave).
// grid 4096, block 128.  wave = bid parity; adds into out3 channels [0,64)
// ---------------------------------------------------------------------------
__global__ __launch_bounds__(128) void k_win(const float* __restrict__ qkv2,
                                             float* __restrict__ out3)
{
    const int half = threadIdx.x >> 6;
    const int bid = blockIdx.x * 2 + half;
    const int n = bid & 7;
    const int win = bid >> 3;
    const int wr = win & 15;
    const int hr = (win >> 4) & 15;
    const int b = win >> 8;
    const int p = threadIdx.x & 63;
    const int wi = p >> 3, wj = p & 7;
    const int h = hr * 8 + wi, w = wr * 8 + wj;
    const size_t row = ((size_t)b * 16384 + h * 128 + w) * 384;

    __shared__ float kk[2][64][8];
    __shared__ float vv[2][64][8];
    float q[8];
#pragma unroll
    for (int d = 0; d < 8; d++) {
        q[d] = qkv2[row + n * 8 + d] * SCALE_F;
        kk[half][p][d] = qkv2[row + 64 + n * 8 + d];
        vv[half][p][d] = qkv2[row + 128 + n * 8 + d];
    }
    __syncthreads();

    float s[64];
    float m = -1e30f;
#pragma unroll
    for (int j = 0; j < 64; j++) {
        float a = 0.f;
#pragma unroll
        for (int d = 0; d < 8; d++) a = fmaf(q[d], kk[half][j][d], a);
        s[j] = a;
        m = fmaxf(m, a);
    }
    float sum = 0.f;
#pragma unroll
    for (int j = 0; j < 64; j++) {
        s[j] = __expf(s[j] - m);
        sum += s[j];
    }
    const float inv = 1.0f / sum;
    float o[8] = {0.f, 0.f, 0.f, 0.f, 0.f, 0.f, 0.f, 0.f};
#pragma unroll
    for (int j = 0; j < 64; j++) {
        const float pj = s[j] * inv;
#pragma unroll
        for (int d = 0; d < 8; d++) o[d] = fmaf(pj, vv[half][j][d], o[d]);
    }
    const size_t orow = ((size_t)b * 16384 + h * 128 + w) * 128;
#pragma unroll
    for (int d = 0; d < 8; d++) out3[orow + n * 8 + d] += o[d];
}

// ---------------------------------------------------------------------------
// K4: routing scores input, BIT-IDENTICAL to the passing scalar path (frozen).
// ---------------------------------------------------------------------------
__global__ __launch_bounds__(128) void k_scores(const float* __restrict__ x,
                       const float* __restrict__ bw, const float* __restrict__ bb,
                       float* __restrict__ pq, float* __restrict__ pk)
{
    const int r = blockIdx.x;
    const int b = r >> 8;
    const int reg = r & 255;
    const int hr = reg >> 4, wr = reg & 15;
    const int c = threadIdx.x;

    float wreg[64];
#pragma unroll
    for (int k = 0; k < 64; k++) wreg[k] = bw[k * 192 + c];
    const float bias = bb[c];

    __shared__ float xs[64][64];
    for (int i = c; i < 64 * 64; i += 128) {
        const int p = i >> 6, ch = i & 63;
        const int h = hr * 8 + (p >> 3), w = wr * 8 + (p & 7);
        xs[p][ch] = x[((size_t)b * 16384 + h * 128 + w) * 128 + 64 + ch];
    }
    __syncthreads();

    float pool = 0.f;
    for (int p = 0; p < 64; p++) {
        float acc = bias;
#pragma unroll
        for (int k = 0; k < 64; k++) acc = fmaf(xs[p][k], wreg[k], acc);
        pool += acc;
    }
    pool *= (1.0f / 64.0f);
    if (c < 64) pq[(size_t)r * 64 + c] = pool;
    else        pk[(size_t)r * 64 + (c - 64)] = pool;
}

// ---------------------------------------------------------------------------
// K5: routing scores + stable top-4.  (frozen)
// ---------------------------------------------------------------------------
__global__ __launch_bounds__(64) void k_topk(const float* __restrict__ pq,
                       const float* __restrict__ pk, int* __restrict__ idx)
{
    const int bi = blockIdx.x;
    const int b = bi >> 8;
    const int t = threadIdx.x;
    __shared__ float qrow[64];
    __shared__ float s[256];
    qrow[t] = pq[(size_t)bi * 64 + t];
    __syncthreads();
    for (int j4 = 0; j4 < 4; j4++) {
        const int j = j4 * 64 + t;
        const float* krow = pk + ((size_t)b * 256 + j) * 64;
        float a = 0.f;
#pragma unroll
        for (int c = 0; c < 64; c++) a = fmaf(qrow[c], krow[c], a);
        s[j] = a;
    }
    __syncthreads();
    if (t == 0) {
        int chosen[4];
        for (int sel = 0; sel < 4; sel++) {
            float best = -1e30f;
            int bj = -1;
            for (int j = 0; j < 256; j++) {
                bool skip = false;
                for (int u = 0; u < sel; u++) skip = skip || (chosen[u] == j);
                if (!skip && s[j] > best) { best = s[j]; bj = j; }
            }
            chosen[sel] = bj;
            idx[bi * 4 + sel] = bj;
        }
    }
}

// ---------------------------------------------------------------------------
// K6: gathered BRA attention, chunked LDS (128 keys/chunk, 8.2 KB) for
// occupancy.  2 waves/block; per chunk wave h takes keys [h*64, h*64+64);
// across 2 chunks each wave covers 128 keys; exact 2-way softmax merge.
// ---------------------------------------------------------------------------
__global__ __launch_bounds__(128) void k_bra(const float* __restrict__ qkv2,
                      const int* __restrict__ idx, float* __restrict__ out3)
{
    const int r = blockIdx.x & 255;
    const int n = (blockIdx.x >> 8) & 7;
    const int b = blockIdx.x >> 11;
    const int tid = threadIdx.x;
    const int q = tid & 63;
    const int half = tid >> 6;

    __shared__ float kk[128][8];
    __shared__ float vv[128][8];
    __shared__ int regs[4];
    if (tid < 4) regs[tid] = idx[((b << 8) + r) * 4 + tid];

    const int hq = (r >> 4) * 8 + (q >> 3), wq = (r & 15) * 8 + (q & 7);
    const size_t qoff = ((size_t)b * 16384 + hq * 128 + wq) * 384 + 192 + n * 8;
    float qv[8];
    {
        const float4 f0 = ((const float4*)(qkv2 + qoff))[0];
        const float4 f1 = ((const float4*)(qkv2 + qoff))[1];
        qv[0] = f0.x * SCALE_F; qv[1] = f0.y * SCALE_F;
        qv[2] = f0.z * SCALE_F; qv[3] = f0.w * SCALE_F;
        qv[4] = f1.x * SCALE_F; qv[5] = f1.y * SCALE_F;
        qv[6] = f1.z * SCALE_F; qv[7] = f1.w * SCALE_F;
    }

    float m = -1e30f, sum = 0.f;
    float o[8] = {0.f, 0.f, 0.f, 0.f, 0.f, 0.f, 0.f, 0.f};

    for (int c = 0; c < 2; c++) {
        __syncthreads();           // regs ready (c=0) / LDS reusable (c=1)
        for (int i = tid; i < 256; i += 128) {
            const int isv = i >> 7;
            const int row = i & 127;
            const int key = c * 128 + row;
            const int rt = regs[key >> 6];
            const int p = key & 63;
            const int hh = (rt >> 4) * 8 + (p >> 3);
            const int ww = (rt & 15) * 8 + (p & 7);
            const float* src = qkv2 + ((size_t)b * 16384 + hh * 128 + ww) * 384
                               + (isv ? 320 : 256) + n * 8;
            float* dst = isv ? &vv[row][0] : &kk[row][0];
            ((float4*)dst)[0] = ((const float4*)src)[0];
            ((float4*)dst)[1] = ((const float4*)src)[1];
        }
        __syncthreads();
        const int base = half * 64;
#pragma unroll
        for (int g = 0; g < 2; g++) {
            const int jb = base + g * 32;
            float s[32];
            float mc = -1e30f;
#pragma unroll
            for (int j = 0; j < 32; j++) {
                float a = 0.f;
#pragma unroll
                for (int d = 0; d < 8; d++) a = fmaf(qv[d], kk[jb + j][d], a);
                s[j] = a;
                mc = fmaxf(mc, a);
            }
            const float m_new = fmaxf(m, mc);
            const float corr = __expf(m - m_new);
            sum *= corr;
#pragma unroll
            for (int d = 0; d < 8; d++) o[d] *= corr;
#pragma unroll
            for (int j = 0; j < 32; j++) {
                const float e = __expf(s[j] - m_new);
                sum += e;
#pragma unroll
                for (int d = 0; d < 8; d++) o[d] = fmaf(e, vv[jb + j][d], o[d]);
            }
            m = m_new;
        }
    }

    // merge the two waves (reuse kk as scratch: 64 q x 12 floats = 3 KB)
    __syncthreads();
    float* st = &kk[0][0];
    if (half == 1) {
        float* p = st + q * 12;
        p[0] = m; p[1] = sum;
#pragma unroll
        for (int d = 0; d < 8; d++) p[2 + d] = o[d];
    }
    __syncthreads();
    if (half == 0) {
        const float* p = st + q * 12;
        const float m1 = p[0], s1 = p[1];
        const float mN = fmaxf(m, m1);
        const float c0 = __expf(m - mN), c1 = __expf(m1 - mN);
        const float inv = 1.0f / (sum * c0 + s1 * c1);
        const size_t orow = ((size_t)b * 16384 + hq * 128 + wq) * 128;
#pragma unroll
        for (int d = 0; d < 8; d++)
            out3[orow + 64 + n * 8 + d] += (o[d] * c0 + p[2 + d] * c1) * inv;
    }
}

// ---------------------------------------------------------------------------
// K9a: channel-attn partial Gram + partial sq-norms.
// ---------------------------------------------------------------------------
__global__ __launch_bounds__(256) void k_cattn_part(const float* __restrict__ cq,
                                                    float* __restrict__ part)
{
    const int bn = blockIdx.x >> 4;
    const int ch = blockIdx.x & 15;
    const int b = bn >> 3, n = bn & 7;
    const int t = threadIdx.x;
    const int d = t >> 4, e = t & 15;
    __shared__ float qs[128][16];
    __shared__ float ks[128][16];
    const float* base = cq + ((size_t)b * 16384 + ch * 1024) * 384;

    float acc = 0.f, nq = 0.f, nk = 0.f;
    for (int l0 = 0; l0 < 1024; l0 += 128) {
        for (int i = t; i < 128 * 32; i += 256) {
            const int pos = i >> 5;
            const int en = i & 31;
            const int col = (en < 16) ? (n * 16 + en) : (128 + n * 16 + en - 16);
            const float v = base[(size_t)(l0 + pos) * 384 + col];
            if (en < 16) qs[pos][en] = v;
            else         ks[pos][en - 16] = v;
        }
        __syncthreads();
#pragma unroll
        for (int l = 0; l < 128; l++) acc = fmaf(qs[l][d], ks[l][e], acc);
#pragma unroll
        for (int l8 = 0; l8 < 8; l8++) {
            const float qv = qs[l8 * 16 + e][d];
            const float kv = ks[l8 * 16 + d][e];
            nq = fmaf(qv, qv, nq);
            nk = fmaf(kv, kv, nk);
        }
        __syncthreads();
    }
    part[((size_t)bn * 16 + ch) * 288 + t] = acc;

    __shared__ float rq[16][17];
    __shared__ float rk[16][17];
    rq[d][e] = nq;
    rk[e][d] = nk;
    __syncthreads();
    if (t < 16) {
        float sq = 0.f, sk = 0.f;
#pragma unroll
        for (int j = 0; j < 16; j++) { sq += rq[t][j]; sk += rk[t][j]; }
        part[((size_t)bn * 16 + ch) * 288 + 256 + t] = sq;
        part[((size_t)bn * 16 + ch) * 288 + 272 + t] = sk;
    }
}

// ---------------------------------------------------------------------------
// K9b: reduce partials, inv-norms, scale, softmax.  grid 32 = bn, block 256
// ---------------------------------------------------------------------------
__global__ __launch_bounds__(256) void k_cattn_red(const float* __restrict__ part,
                        const float* __restrict__ temp, float* __restrict__ cattn)
{
    const int bn = blockIdx.x;
    const int t = threadIdx.x;
    const int d = t >> 4;
    const int e = t & 15;
    float acc = 0.f;
#pragma unroll
    for (int ch = 0; ch < 16; ch++) acc += part[((size_t)bn * 16 + ch) * 288 + t];
    __shared__ float inorm[32];
    if (t < 32) {
        float s = 0.f;
#pragma unroll
        for (int ch = 0; ch < 16; ch++) s += part[((size_t)bn * 16 + ch) * 288 + 256 + t];
        inorm[t] = 1.0f / fmaxf(sqrtf(s), 1e-12f);
    }
    __syncthreads();
    const int n = bn & 7;
    const float scl = inorm[d] * inorm[16 + e] * temp[n];
    __shared__ float S[16][17];
    S[d][e] = acc * scl;
    __syncthreads();
    if (t < 16) {
        float mm = -1e30f;
#pragma unroll
        for (int e2 = 0; e2 < 16; e2++) mm = fmaxf(mm, S[t][e2]);
        float ex[16];
        float ss = 0.f;
#pragma unroll
        for (int e2 = 0; e2 < 16; e2++) {
            ex[e2] = __expf(S[t][e2] - mm);
            ss += ex[e2];
        }
        const float inv = 1.0f / ss;
#pragma unroll
        for (int e2 = 0; e2 < 16; e2++) cattn[(bn * 16 + t) * 16 + e2] = ex[e2] * inv;
    }
}

// ---------------------------------------------------------------------------
// K10: cout = cattn @ cv (position-major cv), written (B, L, 128) into out3
// grid 8192 = (bn, l/64), block 64
// ---------------------------------------------------------------------------
__global__ __launch_bounds__(64) void k_cout(const float* __restrict__ cattn,
                       const float* __restrict__ cq, float* __restrict__ out3)
{
    const int blk = blockIdx.x;
    const int bn = blk >> 8;
    const int b = bn >> 3, n = bn & 7;
    const int l0 = (blk & 255) * 64;
    const int t = threadIdx.x;
    __shared__ float A[16][17];
    for (int i = t; i < 256; i += 64) A[i >> 4][i & 15] = cattn[bn * 256 + i];
    __syncthreads();
    const int pos = l0 + t;
    const float* vp = cq + ((size_t)b * 16384 + pos) * 384 + 256 + n * 16;
    float v[16];
#pragma unroll
    for (int e4 = 0; e4 < 4; e4++) {
        const float4 f = ((const float4*)vp)[e4];
        v[e4 * 4 + 0] = f.x; v[e4 * 4 + 1] = f.y; v[e4 * 4 + 2] = f.z; v[e4 * 4 + 3] = f.w;
    }
    float acc[16];
#pragma unroll
    for (int d = 0; d < 16; d++) acc[d] = 0.f;
#pragma unroll
    for (int e = 0; e < 16; e++) {
#pragma unroll
        for (int d = 0; d < 16; d++) acc[d] = fmaf(A[d][e], v[e], acc[d]);
    }
    float* op = out3 + ((size_t)b * 16384 + pos) * 128 + n * 16;
#pragma unroll
    for (int d4 = 0; d4 < 4; d4++) {
        float4 f;
        f.x = acc[d4 * 4 + 0]; f.y = acc[d4 * 4 + 1]; f.z = acc[d4 * 4 + 2]; f.w = acc[d4 * 4 + 3];
        ((float4*)op)[d4] = f;
    }
}

// ---------------------------------------------------------------------------
extern "C" void kernel_launch(void* const* d_in, const int* in_sizes, int n_in,
                              void* d_out, int out_size, void* d_ws, size_t ws_size,
                              hipStream_t stream)
{
    const float* x       = (const float*)d_in[0];
    const float* wqkv_w  = (const float*)d_in[1];
    const float* wqkv_b  = (const float*)d_in[2];
    const float* bqkv_w  = (const float*)d_in[3];
    const float* bqkv_b  = (const float*)d_in[4];
    const float* lepe_w  = (const float*)d_in[5];
    const float* lepe_b  = (const float*)d_in[6];
    const float* ca_qkv_w = (const float*)d_in[7];
    const float* ca_qkv_b = (const float*)d_in[8];
    const float* ca_temp  = (const float*)d_in[9];
    const float* ca_proj_w = (const float*)d_in[10];
    const float* ca_proj_b = (const float*)d_in[11];

    float* ws = (float*)d_ws;
    float* qkv2 = ws;                         // 65536*384 floats (pos-major)
    float* cqkv = ws;                         // alias (qkv2 dead after k_bra)
    float* out3 = ws + 25165824;              // 65536*128 floats
    float* aux  = out3 + 8388608;             // aux region
    float* pq   = aux;                        // 65536 (dead after k_topk)
    float* pk   = pq + 65536;                 // 65536 (dead after k_topk)
    int*   idx  = (int*)(pk + 65536);         // 4096 ints (dead after k_bra)
    float* part = aux;                        // alias pq..idx: 147456
    float* catn = aux + 147456;               // 8192
    ushort* wt1h = (ushort*)aux;              // aliases aux (dead before k_scores)
    ushort* wt1l = (ushort*)(aux + 24576);
    float* tail = aux + 155648;
    ushort* wt2h = (ushort*)tail;
    ushort* wt2l = (ushort*)(tail + 24576);
    ushort* wt3h = (ushort*)(tail + 49152);
    ushort* wt3l = (ushort*)(tail + 57344);

    k_pack<<<896, 128, 0, stream>>>(wqkv_w, bqkv_w, ca_qkv_w, ca_proj_w,
                                    wt1h, wt1l, wt2h, wt2l, wt3h, wt3l);
    k_gemm<<<dim3(1024, 3), 256, 0, stream>>>(x, wt1h, wt1l,
                                              wqkv_b, bqkv_b, 192, qkv2, 384);
    k_conv<<<8192, 128, 0, stream>>>(qkv2, lepe_w, lepe_b, out3);
    k_win<<<4096, 128, 0, stream>>>(qkv2, out3);
    k_scores<<<1024, 128, 0, stream>>>(x, bqkv_w, bqkv_b, pq, pk);
    k_topk<<<1024, 64, 0, stream>>>(pq, pk, idx);
    k_bra<<<8192, 128, 0, stream>>>(qkv2, idx, out3);
    k_gemm<<<dim3(1024, 3), 256, 0, stream>>>(out3, wt2h, wt2l,
                                              ca_qkv_b, ca_qkv_b, 384, cqkv, 384);
    k_cattn_part<<<512, 256, 0, stream>>>(cqkv, part);
    k_cattn_red<<<32, 256, 0, stream>>>(part, ca_temp, catn);
    k_cout<<<8192, 64, 0, stream>>>(catn, cqkv, out3);
    k_gemm<<<dim3(1024, 1), 256, 0, stream>>>(out3, wt3h, wt3l,
                                              ca_proj_b, ca_proj_b, 128,
                                              (float*)d_out, 128);
}